// Round 6
// baseline (346.322 us; speedup 1.0000x reference)
//
#include <hip/hip_runtime.h>
#include <hip/hip_bf16.h>
#include <math.h>

typedef __attribute__((ext_vector_type(8))) short bf16x8;
typedef __attribute__((ext_vector_type(4))) short bf16x4;
typedef __attribute__((ext_vector_type(4))) float f32x4;

__device__ __forceinline__ unsigned short f2bf(float f) {
    union { float f; unsigned int u; } v; v.f = f;
    unsigned int u = v.u;
    u += 0x7fffu + ((u >> 16) & 1u);   // round-to-nearest-even
    return (unsigned short)(u >> 16);
}

__device__ __forceinline__ f32x4 mfma16(bf16x4 a, bf16x4 b, f32x4 c) {
#if __has_builtin(__builtin_amdgcn_mfma_f32_16x16x16bf16_1k)
    return __builtin_amdgcn_mfma_f32_16x16x16bf16_1k(a, b, c, 0, 0, 0);
#else
    asm volatile("v_mfma_f32_16x16x16_bf16 %0, %1, %2, %0\n\ts_nop 7"
                 : "+v"(c) : "v"(a), "v"(b));
    return c;
#endif
}

__device__ __forceinline__ unsigned packbf2(float a, float b) {
    __hip_bfloat162 h = __float22bfloat162_rn(float2{a, b});
    union { __hip_bfloat162 h; unsigned u; } v; v.h = h;
    return v.u;
}

__device__ __forceinline__ float fmax3(float a, float b, float c) {
    return fmaxf(fmaxf(a, b), c);   // clang fuses to v_max3_f32
}

// ---------------------------------------------------------------------------
// Shared GEMM body: C[m][n] = sum_k A[m][k] * W[n][k] + bias[n]
// M=8192, N=512, K=512. 128x128 tile, BK=32, 256 threads (4 waves 2x2).
// Loads for k-tile t+1 issue AFTER the second barrier (latency hides under
// the 16-MFMA compute phase instead of being drained at the barrier).
// ---------------------------------------------------------------------------
template<int A_BF16>
__device__ __forceinline__ void gemm_body(const void* Ap, const float* W,
                                          f32x4 (&acc)[4][4],
                                          unsigned short (*As)[40], unsigned short (*Bs)[40],
                                          int bm, int bn, int t)
{
    constexpr int Kdim = 512;
    const int lane = t & 63, g = lane >> 4, c = lane & 15;
    const int w = t >> 6, wr = w >> 1, wc = w & 1;

    uint4  paB[2];
    float4 paF[4];
    float4 pw[4];
    const int ccB = (t & 3) * 8, r0B = t >> 2;
    const int c4  = (t & 7) * 4, r0F = t >> 3;

    if (A_BF16) {
        const unsigned short* A = (const unsigned short*)Ap;
        for (int p = 0; p < 2; ++p)
            paB[p] = *(const uint4*)(A + (size_t)(bm + r0B + p * 64) * Kdim + ccB);
    } else {
        const float* A = (const float*)Ap;
        for (int p = 0; p < 4; ++p)
            paF[p] = *(const float4*)(A + (size_t)(bm + r0F + p * 32) * Kdim + c4);
    }
    for (int p = 0; p < 4; ++p)
        pw[p] = *(const float4*)(W + (size_t)(bn + r0F + p * 32) * Kdim + c4);

    for (int k0 = 0; k0 < Kdim; k0 += 32) {
        __syncthreads();
        if (A_BF16) {
            for (int p = 0; p < 2; ++p)
                *(uint4*)&As[r0B + p * 64][ccB] = paB[p];
        } else {
            for (int p = 0; p < 4; ++p) {
                float4 v = paF[p];
                ushort4 hv;
                hv.x = f2bf(v.x); hv.y = f2bf(v.y); hv.z = f2bf(v.z); hv.w = f2bf(v.w);
                *(ushort4*)&As[r0F + p * 32][c4] = hv;
            }
        }
        for (int p = 0; p < 4; ++p) {
            float4 v = pw[p];
            ushort4 hv;
            hv.x = f2bf(v.x); hv.y = f2bf(v.y); hv.z = f2bf(v.z); hv.w = f2bf(v.w);
            *(ushort4*)&Bs[r0F + p * 32][c4] = hv;
        }
        __syncthreads();
        if (k0 + 32 < Kdim) {
            const int kn = k0 + 32;
            if (A_BF16) {
                const unsigned short* A = (const unsigned short*)Ap;
                for (int p = 0; p < 2; ++p)
                    paB[p] = *(const uint4*)(A + (size_t)(bm + r0B + p * 64) * Kdim + kn + ccB);
            } else {
                const float* A = (const float*)Ap;
                for (int p = 0; p < 4; ++p)
                    paF[p] = *(const float4*)(A + (size_t)(bm + r0F + p * 32) * Kdim + kn + c4);
            }
            for (int p = 0; p < 4; ++p)
                pw[p] = *(const float4*)(W + (size_t)(bn + r0F + p * 32) * Kdim + kn + c4);
        }
        bf16x8 af[4], bfr[4];
        for (int i = 0; i < 4; ++i)
            af[i] = *(const bf16x8*)&As[wr * 64 + i * 16 + c][g * 8];
        for (int j = 0; j < 4; ++j)
            bfr[j] = *(const bf16x8*)&Bs[wc * 64 + j * 16 + c][g * 8];
        for (int i = 0; i < 4; ++i)
            for (int j = 0; j < 4; ++j)
                acc[i][j] = __builtin_amdgcn_mfma_f32_16x16x32_bf16(af[i], bfr[j], acc[i][j], 0, 0, 0);
    }
}

// Fused Q/K/V projections: blockIdx.z selects weight set. q fp32 input.
__global__ __launch_bounds__(256, 2)
void gemm_qkv(const float* __restrict__ q,
              const float* __restrict__ Wq, const float* __restrict__ bq,
              const float* __restrict__ Wk, const float* __restrict__ bk,
              const float* __restrict__ Wv, const float* __restrict__ bv,
              unsigned short* __restrict__ Qo, unsigned short* __restrict__ Ko,
              unsigned short* __restrict__ Vo)
{
    __shared__ unsigned short As[128][40];
    __shared__ unsigned short Bs[128][40];
    const int t = threadIdx.x, z = blockIdx.z;
    const int lane = t & 63, g = lane >> 4, c = lane & 15;
    const int w = t >> 6, wr = w >> 1, wc = w & 1;
    const int bm = blockIdx.x * 128, bn = blockIdx.y * 128;

    const float* W    = (z == 0) ? Wq : (z == 1) ? Wk : Wv;
    const float* bias = (z == 0) ? bq : (z == 1) ? bk : bv;
    unsigned short* Out = (z == 0) ? Qo : (z == 1) ? Ko : Vo;

    f32x4 acc[4][4] = {};
    gemm_body<0>((const void*)q, W, acc, As, Bs, bm, bn, t);

    float bv4[4];
    for (int j = 0; j < 4; ++j) bv4[j] = bias[bn + wc * 64 + j * 16 + c];
    for (int i = 0; i < 4; ++i)
        for (int j = 0; j < 4; ++j)
            for (int r = 0; r < 4; ++r) {
                int m = bm + wr * 64 + i * 16 + 4 * g + r;
                int n = bn + wc * 64 + j * 16 + c;
                float val = acc[i][j][r] + bv4[j];
                int b = m >> 12, s = m & 4095, h = n >> 6, d = n & 63;
                if (z < 2)
                    Out[((((size_t)b * 8 + h) * 4096 + s) << 6) + d] = f2bf(val);
                else
                    Out[(((size_t)b * 8 + h) * 64 + d) * 4096 + s] = f2bf(val);
            }
}

// Output projection: A bf16 [8192][512], out fp32 [8192][512].
__global__ __launch_bounds__(256, 2)
void gemm_out(const unsigned short* __restrict__ A, const float* __restrict__ W,
              const float* __restrict__ bias, float* __restrict__ Out)
{
    __shared__ unsigned short As[128][40];
    __shared__ unsigned short Bs[128][40];
    const int t = threadIdx.x;
    const int lane = t & 63, g = lane >> 4, c = lane & 15;
    const int w = t >> 6, wr = w >> 1, wc = w & 1;
    const int bm = blockIdx.x * 128, bn = blockIdx.y * 128;

    f32x4 acc[4][4] = {};
    gemm_body<1>((const void*)A, W, acc, As, Bs, bm, bn, t);

    float bv4[4];
    for (int j = 0; j < 4; ++j) bv4[j] = bias[bn + wc * 64 + j * 16 + c];
    for (int i = 0; i < 4; ++i)
        for (int j = 0; j < 4; ++j)
            for (int r = 0; r < 4; ++r) {
                int m = bm + wr * 64 + i * 16 + 4 * g + r;
                int n = bn + wc * 64 + j * 16 + c;
                Out[(size_t)m * 512 + n] = acc[i][j][r] + bv4[j];
            }
}

// ---------------------------------------------------------------------------
// Flash attention fwd. Q,K: [16][4096][64] bf16; VT: [16][64][4096] bf16.
// 4 waves, 64 Q-rows (16/wave), KV-tile 128 (2 softmax halves per barrier).
// LDS: K [128][64], V^T [64][128], row stride = 0 mod 32 banks, 16B-slot
// XOR swizzle (slot ^= row&7) applied on BOTH write and read -> all LDS
// accesses (b128 reads, b64 reads, b128 writes) verified conflict-free.
// Swapped QK^T; per-lane softmax; l via ones-column MFMA; setprio on MFMA.
// ---------------------------------------------------------------------------
__global__ __launch_bounds__(256, 2)
void attn64(const unsigned short* __restrict__ Q, const unsigned short* __restrict__ Kh,
            const unsigned short* __restrict__ VT, unsigned short* __restrict__ Mo)
{
    __shared__ unsigned short Ks[128 * 64];   // [key][d], 8 slots/row, swizzled
    __shared__ unsigned short Vs[64 * 128];   // [d][key], 16 slots/row, swizzled

    const int t = threadIdx.x, w = t >> 6, lane = t & 63, g = lane >> 4, c = lane & 15;
    // XCD-aware swizzle: 1024 blocks, 8 XCDs, bijective.
    const int idp = (blockIdx.x & 7) * 128 + (blockIdx.x >> 3);
    const int bh = idp >> 6;
    const int q0 = (idp & 63) * 64;
    const unsigned short* Qb = Q + (size_t)bh * 4096 * 64;
    const unsigned short* Kb = Kh + (size_t)bh * 4096 * 64;
    const unsigned short* Vb = VT + (size_t)bh * 64 * 4096;

    bf16x8 qf[2];
    {
        int qr = q0 + w * 16 + c;
        qf[0] = *(const bf16x8*)(Qb + (size_t)qr * 64 + g * 8);
        qf[1] = *(const bf16x8*)(Qb + (size_t)qr * 64 + 32 + g * 8);
    }

    f32x4 o[4] = {};          // o[nd][r] = O[q-local 4g+r][d = nd*16+c]
    f32x4 lacc = {};          // lacc[r] = l for q-row 4g+r
    float nm2 = 0.f;          // -m for this lane's q-row (c); exp2 domain

    bf16x4 ones;
    ones[0] = ones[1] = ones[2] = ones[3] = (short)0x3F80;   // bf16 1.0

    // staging: K tile 128x64 (4 slots/thread), V tile 64x128 (4 slots/thread)
    const int krow = t >> 1, kcol = (t & 1) * 32;        // shorts
    const int vrow = t >> 2, vcol = (t & 3) * 32;        // shorts (keys)
    int kwoff[4], vwoff[4];
    for (int b2 = 0; b2 < 4; ++b2) {
        kwoff[b2] = krow * 64 + ((((kcol >> 3) + b2) ^ (krow & 7)) << 3);
        vwoff[b2] = vrow * 128 + ((((vcol >> 3) + b2) ^ (vrow & 7)) << 3);
    }
    const unsigned short* kp0 = Kb + (size_t)krow * 64 + kcol;
    const unsigned short* vp0 = Vb + (size_t)vrow * 4096 + vcol;

    uint4 ka[4], va[4];
    for (int b2 = 0; b2 < 4; ++b2) {
        ka[b2] = *(const uint4*)(kp0 + b2 * 8);
        va[b2] = *(const uint4*)(vp0 + b2 * 8);
    }

    const float sc2 = 0.125f * 1.44269504f;   // scale * log2(e)
    const float THR = 10.f;                   // p bounded by 2^10
    const int c7 = c & 7;

    for (int jt = 0; jt < 32; ++jt) {
        __syncthreads();
        for (int b2 = 0; b2 < 4; ++b2) {
            *(uint4*)&Ks[kwoff[b2]] = ka[b2];
            *(uint4*)&Vs[vwoff[b2]] = va[b2];
        }
        __syncthreads();
        // next tile's loads issue after the barrier: fly across compute
        if (jt < 31) {
            const unsigned short* kp = kp0 + (size_t)(jt + 1) * 128 * 64;
            const unsigned short* vp = vp0 + (jt + 1) * 128;
            for (int b2 = 0; b2 < 4; ++b2) {
                ka[b2] = *(const uint4*)(kp + b2 * 8);
                va[b2] = *(const uint4*)(vp + b2 * 8);
            }
        }

        for (int half = 0; half < 2; ++half) {
            // S^T = K Q^T: t4[nt][r] = S[q=c][key] * sc2 - m
            f32x4 t4[4];
            __builtin_amdgcn_s_setprio(1);
            for (int nt = 0; nt < 4; ++nt) {
                int row = (half * 4 + nt) * 16 + c;
                bf16x8 kf0 = *(const bf16x8*)&Ks[row * 64 + ((g ^ c7) << 3)];
                bf16x8 kf1 = *(const bf16x8*)&Ks[row * 64 + (((4 + g) ^ c7) << 3)];
                f32x4 z = {};
                z = __builtin_amdgcn_mfma_f32_16x16x32_bf16(kf0, qf[0], z, 0, 0, 0);
                z = __builtin_amdgcn_mfma_f32_16x16x32_bf16(kf1, qf[1], z, 0, 0, 0);
                for (int r = 0; r < 4; ++r) t4[nt][r] = fmaf(z[r], sc2, nm2);
            }
            __builtin_amdgcn_s_setprio(0);

            // per-lane max of 16 via max3 tree
            float ma = fmax3(t4[0][0], t4[0][1], t4[0][2]);
            float mb = fmax3(t4[0][3], t4[1][0], t4[1][1]);
            float mc = fmax3(t4[1][2], t4[1][3], t4[2][0]);
            float md = fmax3(t4[2][1], t4[2][2], t4[2][3]);
            float me = fmax3(t4[3][0], t4[3][1], t4[3][2]);
            float tm = fmax3(fmax3(ma, mb, mc), fmax3(md, me, t4[3][3]), -3.0e38f);
            if (!__all(tm <= THR)) {
                // rare: reduce max across the 4 g-groups (same q-row c)
                float pm = tm;
                pm = fmaxf(pm, __shfl_xor(pm, 16));
                pm = fmaxf(pm, __shfl_xor(pm, 32));
                float dm = fmaxf(pm, 0.f);
                nm2 -= dm;
                float alpha = exp2f(-dm);
                for (int nt = 0; nt < 4; ++nt)
                    for (int r = 0; r < 4; ++r) t4[nt][r] -= dm;
                for (int r = 0; r < 4; ++r) {
                    float ar = __shfl(alpha, 4 * g + r);
                    for (int nd = 0; nd < 4; ++nd) o[nd][r] *= ar;
                    lacc[r] *= ar;
                }
            }

            // p = 2^t, pack to mfma16 A-fragments
            bf16x4 pf[4];
            for (int nt = 0; nt < 4; ++nt) {
                float p0 = exp2f(t4[nt][0]), p1 = exp2f(t4[nt][1]);
                float p2 = exp2f(t4[nt][2]), p3 = exp2f(t4[nt][3]);
                union { unsigned u[2]; bf16x4 v; } pk;
                pk.u[0] = packbf2(p0, p1);
                pk.u[1] = packbf2(p2, p3);
                pf[nt] = pk.v;
            }

            // O += P V ; l += P * ones
            __builtin_amdgcn_s_setprio(1);
            for (int nd = 0; nd < 4; ++nd) {
                int row = nd * 16 + c;
                for (int nt = 0; nt < 4; ++nt) {
                    int slot = (2 * (half * 4 + nt) + (g >> 1)) ^ c7;
                    bf16x4 vf = *(const bf16x4*)&Vs[row * 128 + (slot << 3) + ((g & 1) << 2)];
                    o[nd] = mfma16(pf[nt], vf, o[nd]);
                }
            }
            for (int nt = 0; nt < 4; ++nt)
                lacc = mfma16(pf[nt], ones, lacc);
            __builtin_amdgcn_s_setprio(0);
        }
    }

    const int b = bh >> 3, h = bh & 7;
    for (int r = 0; r < 4; ++r) {
        float inv = 1.f / lacc[r];
        int m = b * 4096 + q0 + w * 16 + 4 * g + r;
        for (int nd = 0; nd < 4; ++nd) {
            int n = h * 64 + nd * 16 + c;
            Mo[(size_t)m * 512 + n] = f2bf(o[nd][r] * inv);
        }
    }
}

extern "C" void kernel_launch(void* const* d_in, const int* in_sizes, int n_in,
                              void* d_out, int out_size, void* d_ws, size_t ws_size,
                              hipStream_t stream) {
    const float* q  = (const float*)d_in[0];
    const float* Wq = (const float*)d_in[1];
    const float* bq = (const float*)d_in[2];
    const float* Wk = (const float*)d_in[3];
    const float* bk = (const float*)d_in[4];
    const float* Wv = (const float*)d_in[5];
    const float* bv = (const float*)d_in[6];
    const float* Wo = (const float*)d_in[7];
    const float* bo = (const float*)d_in[8];

    unsigned short* Qb = (unsigned short*)d_ws;            // 8 MB
    unsigned short* Kb = Qb + (size_t)16 * 4096 * 64;      // 8 MB
    unsigned short* Vt = Kb + (size_t)16 * 4096 * 64;      // 8 MB (V^T per head)
    unsigned short* Mg = Vt + (size_t)16 * 4096 * 64;      // merged bf16 [8192][512]

    dim3 gb(256);
    dim3 gqkv(64, 4, 3);
    gemm_qkv<<<gqkv, gb, 0, stream>>>(q, Wq, bq, Wk, bk, Wv, bv, Qb, Kb, Vt);

    dim3 ga(1024);
    attn64<<<ga, gb, 0, stream>>>(Qb, Kb, Vt, Mg);

    dim3 gg(64, 4);
    gemm_out<<<gg, gb, 0, stream>>>(Mg, Wo, bo, (float*)d_out);
}

// Round 7
// 199.320 us; speedup vs baseline: 1.7375x; 1.7375x over previous
//
#include <hip/hip_runtime.h>
#include <hip/hip_bf16.h>
#include <math.h>

typedef __attribute__((ext_vector_type(8))) short bf16x8;
typedef __attribute__((ext_vector_type(4))) short bf16x4;
typedef __attribute__((ext_vector_type(4))) float f32x4;

__device__ __forceinline__ unsigned short f2bf(float f) {
    union { float f; unsigned int u; } v; v.f = f;
    unsigned int u = v.u;
    u += 0x7fffu + ((u >> 16) & 1u);   // round-to-nearest-even
    return (unsigned short)(u >> 16);
}

__device__ __forceinline__ f32x4 mfma16(bf16x4 a, bf16x4 b, f32x4 c) {
#if __has_builtin(__builtin_amdgcn_mfma_f32_16x16x16bf16_1k)
    return __builtin_amdgcn_mfma_f32_16x16x16bf16_1k(a, b, c, 0, 0, 0);
#else
    asm volatile("v_mfma_f32_16x16x16_bf16 %0, %1, %2, %0\n\ts_nop 7"
                 : "+v"(c) : "v"(a), "v"(b));
    return c;
#endif
}

__device__ __forceinline__ unsigned packbf2(float a, float b) {
    __hip_bfloat162 h = __float22bfloat162_rn(float2{a, b});
    union { __hip_bfloat162 h; unsigned u; } v; v.h = h;
    return v.u;
}

__device__ __forceinline__ float fmax3(float a, float b, float c) {
    return fmaxf(fmaxf(a, b), c);   // clang fuses to v_max3_f32
}

// ---------------------------------------------------------------------------
// Shared GEMM body: C[m][n] = sum_k A[m][k] * W[n][k] + bias[n]
// M=8192, N=512, K=512. 128x128 tile, BK=32, 256 threads (4 waves 2x2).
// Loads for k-tile t+1 issue AFTER the second barrier (latency hides under
// the 16-MFMA compute phase instead of being drained at the barrier).
// ---------------------------------------------------------------------------
template<int A_BF16>
__device__ __forceinline__ void gemm_body(const void* Ap, const float* W,
                                          f32x4 (&acc)[4][4],
                                          unsigned short (*As)[40], unsigned short (*Bs)[40],
                                          int bm, int bn, int t)
{
    constexpr int Kdim = 512;
    const int lane = t & 63, g = lane >> 4, c = lane & 15;
    const int w = t >> 6, wr = w >> 1, wc = w & 1;

    uint4  paB[2];
    float4 paF[4];
    float4 pw[4];
    const int ccB = (t & 3) * 8, r0B = t >> 2;
    const int c4  = (t & 7) * 4, r0F = t >> 3;

    if (A_BF16) {
        const unsigned short* A = (const unsigned short*)Ap;
        for (int p = 0; p < 2; ++p)
            paB[p] = *(const uint4*)(A + (size_t)(bm + r0B + p * 64) * Kdim + ccB);
    } else {
        const float* A = (const float*)Ap;
        for (int p = 0; p < 4; ++p)
            paF[p] = *(const float4*)(A + (size_t)(bm + r0F + p * 32) * Kdim + c4);
    }
    for (int p = 0; p < 4; ++p)
        pw[p] = *(const float4*)(W + (size_t)(bn + r0F + p * 32) * Kdim + c4);

    for (int k0 = 0; k0 < Kdim; k0 += 32) {
        __syncthreads();
        if (A_BF16) {
            for (int p = 0; p < 2; ++p)
                *(uint4*)&As[r0B + p * 64][ccB] = paB[p];
        } else {
            for (int p = 0; p < 4; ++p) {
                float4 v = paF[p];
                ushort4 hv;
                hv.x = f2bf(v.x); hv.y = f2bf(v.y); hv.z = f2bf(v.z); hv.w = f2bf(v.w);
                *(ushort4*)&As[r0F + p * 32][c4] = hv;
            }
        }
        for (int p = 0; p < 4; ++p) {
            float4 v = pw[p];
            ushort4 hv;
            hv.x = f2bf(v.x); hv.y = f2bf(v.y); hv.z = f2bf(v.z); hv.w = f2bf(v.w);
            *(ushort4*)&Bs[r0F + p * 32][c4] = hv;
        }
        __syncthreads();
        if (k0 + 32 < Kdim) {
            const int kn = k0 + 32;
            if (A_BF16) {
                const unsigned short* A = (const unsigned short*)Ap;
                for (int p = 0; p < 2; ++p)
                    paB[p] = *(const uint4*)(A + (size_t)(bm + r0B + p * 64) * Kdim + kn + ccB);
            } else {
                const float* A = (const float*)Ap;
                for (int p = 0; p < 4; ++p)
                    paF[p] = *(const float4*)(A + (size_t)(bm + r0F + p * 32) * Kdim + kn + c4);
            }
            for (int p = 0; p < 4; ++p)
                pw[p] = *(const float4*)(W + (size_t)(bn + r0F + p * 32) * Kdim + kn + c4);
        }
        bf16x8 af[4], bfr[4];
        for (int i = 0; i < 4; ++i)
            af[i] = *(const bf16x8*)&As[wr * 64 + i * 16 + c][g * 8];
        for (int j = 0; j < 4; ++j)
            bfr[j] = *(const bf16x8*)&Bs[wc * 64 + j * 16 + c][g * 8];
        for (int i = 0; i < 4; ++i)
            for (int j = 0; j < 4; ++j)
                acc[i][j] = __builtin_amdgcn_mfma_f32_16x16x32_bf16(af[i], bfr[j], acc[i][j], 0, 0, 0);
    }
}

// Fused Q/K/V projections: blockIdx.z selects weight set. q fp32 input.
__global__ __launch_bounds__(256, 2)
void gemm_qkv(const float* __restrict__ q,
              const float* __restrict__ Wq, const float* __restrict__ bq,
              const float* __restrict__ Wk, const float* __restrict__ bk,
              const float* __restrict__ Wv, const float* __restrict__ bv,
              unsigned short* __restrict__ Qo, unsigned short* __restrict__ Ko,
              unsigned short* __restrict__ Vo)
{
    __shared__ unsigned short As[128][40];
    __shared__ unsigned short Bs[128][40];
    const int t = threadIdx.x, z = blockIdx.z;
    const int lane = t & 63, g = lane >> 4, c = lane & 15;
    const int w = t >> 6, wr = w >> 1, wc = w & 1;
    const int bm = blockIdx.x * 128, bn = blockIdx.y * 128;

    const float* W    = (z == 0) ? Wq : (z == 1) ? Wk : Wv;
    const float* bias = (z == 0) ? bq : (z == 1) ? bk : bv;
    unsigned short* Out = (z == 0) ? Qo : (z == 1) ? Ko : Vo;

    f32x4 acc[4][4] = {};
    gemm_body<0>((const void*)q, W, acc, As, Bs, bm, bn, t);

    float bv4[4];
    for (int j = 0; j < 4; ++j) bv4[j] = bias[bn + wc * 64 + j * 16 + c];
    for (int i = 0; i < 4; ++i)
        for (int j = 0; j < 4; ++j)
            for (int r = 0; r < 4; ++r) {
                int m = bm + wr * 64 + i * 16 + 4 * g + r;
                int n = bn + wc * 64 + j * 16 + c;
                float val = acc[i][j][r] + bv4[j];
                int b = m >> 12, s = m & 4095, h = n >> 6, d = n & 63;
                if (z < 2)
                    Out[((((size_t)b * 8 + h) * 4096 + s) << 6) + d] = f2bf(val);
                else
                    Out[(((size_t)b * 8 + h) * 64 + d) * 4096 + s] = f2bf(val);
            }
}

// Output projection: A bf16 [8192][512], out fp32 [8192][512].
__global__ __launch_bounds__(256, 2)
void gemm_out(const unsigned short* __restrict__ A, const float* __restrict__ W,
              const float* __restrict__ bias, float* __restrict__ Out)
{
    __shared__ unsigned short As[128][40];
    __shared__ unsigned short Bs[128][40];
    const int t = threadIdx.x;
    const int lane = t & 63, g = lane >> 4, c = lane & 15;
    const int w = t >> 6, wr = w >> 1, wc = w & 1;
    const int bm = blockIdx.x * 128, bn = blockIdx.y * 128;

    f32x4 acc[4][4] = {};
    gemm_body<1>((const void*)A, W, acc, As, Bs, bm, bn, t);

    float bv4[4];
    for (int j = 0; j < 4; ++j) bv4[j] = bias[bn + wc * 64 + j * 16 + c];
    for (int i = 0; i < 4; ++i)
        for (int j = 0; j < 4; ++j)
            for (int r = 0; r < 4; ++r) {
                int m = bm + wr * 64 + i * 16 + 4 * g + r;
                int n = bn + wc * 64 + j * 16 + c;
                Out[(size_t)m * 512 + n] = acc[i][j][r] + bv4[j];
            }
}

// ---------------------------------------------------------------------------
// Flash attention fwd. Q,K: [16][4096][64] bf16; VT: [16][64][4096] bf16.
// 4 waves, 64 Q-rows (16/wave), KV-tile 64. Round-5 control flow (named
// prefetch regs, single compute phase) + conflict-free LDS: stride 64
// (== 0 mod 32 banks) with 16B-slot XOR swizzle slot^=(row&7) on BOTH the
// staging writes and the fragment reads. All LDS accesses at bank minimum.
// Swapped QK^T; per-lane softmax; l via ones-column MFMA; XCD swizzle.
// ---------------------------------------------------------------------------
__global__ __launch_bounds__(256, 2)
void attn64(const unsigned short* __restrict__ Q, const unsigned short* __restrict__ Kh,
            const unsigned short* __restrict__ VT, unsigned short* __restrict__ Mo)
{
    __shared__ unsigned short Ks[64 * 64];   // [key][d], swizzled slots
    __shared__ unsigned short Vs[64 * 64];   // [d][key], swizzled slots

    const int t = threadIdx.x, w = t >> 6, lane = t & 63, g = lane >> 4, c = lane & 15;
    // XCD-aware swizzle: 1024 blocks, 8 XCDs, bijective.
    const int idp = (blockIdx.x & 7) * 128 + (blockIdx.x >> 3);
    const int bh = idp >> 6;
    const int q0 = (idp & 63) * 64;
    const unsigned short* Qb = Q + (size_t)bh * 4096 * 64;
    const unsigned short* Kb = Kh + (size_t)bh * 4096 * 64;
    const unsigned short* Vb = VT + (size_t)bh * 64 * 4096;

    bf16x8 qf[2];
    {
        int qr = q0 + w * 16 + c;
        qf[0] = *(const bf16x8*)(Qb + (size_t)qr * 64 + g * 8);
        qf[1] = *(const bf16x8*)(Qb + (size_t)qr * 64 + 32 + g * 8);
    }

    f32x4 o[4] = {};          // o[nd][r] = O[q-local 4g+r][d = nd*16+c]
    f32x4 lacc = {};          // lacc[r] = l for q-row 4g+r
    float nm2 = 0.f;          // -m for this lane's q-row (c); exp2 domain

    bf16x4 ones;
    ones[0] = ones[1] = ones[2] = ones[3] = (short)0x3F80;   // bf16 1.0

    // staging: row = t>>2 (64 rows), 2 slots per thread starting at (t&3)*2
    const int srow = t >> 2, scol = (t & 3) * 16;
    const int s0 = (t & 3) * 2, r7 = srow & 7;
    const int woff0 = srow * 64 + ((s0 ^ r7) << 3);
    const int woff1 = srow * 64 + (((s0 + 1) ^ r7) << 3);
    const unsigned short* kp0 = Kb + (size_t)srow * 64 + scol;
    const unsigned short* vp0 = Vb + (size_t)srow * 4096 + scol;

    uint4 ka0 = *(const uint4*)(kp0);
    uint4 ka1 = *(const uint4*)(kp0 + 8);
    uint4 va0 = *(const uint4*)(vp0);
    uint4 va1 = *(const uint4*)(vp0 + 8);

    const float sc2 = 0.125f * 1.44269504f;   // scale * log2(e)
    const float THR = 10.f;                   // p bounded by 2^10
    const int c7 = c & 7;

    for (int jt = 0; jt < 64; ++jt) {
        __syncthreads();
        *(uint4*)&Ks[woff0] = ka0;
        *(uint4*)&Ks[woff1] = ka1;
        *(uint4*)&Vs[woff0] = va0;
        *(uint4*)&Vs[woff1] = va1;
        __syncthreads();
        // issue next tile's loads AFTER the barrier: they fly across compute
        if (jt < 63) {
            const unsigned short* kp = kp0 + (size_t)(jt + 1) * 4096;
            ka0 = *(const uint4*)(kp);
            ka1 = *(const uint4*)(kp + 8);
            const unsigned short* vp = vp0 + (jt + 1) * 64;
            va0 = *(const uint4*)(vp);
            va1 = *(const uint4*)(vp + 8);
        }

        // S^T = K Q^T: t4[nt][r] = S[q=c][key=16nt+4g+r] * sc2 - m
        f32x4 t4[4];
        for (int nt = 0; nt < 4; ++nt) {
            int row = nt * 16 + c;
            bf16x8 kf0 = *(const bf16x8*)&Ks[row * 64 + ((g ^ c7) << 3)];
            bf16x8 kf1 = *(const bf16x8*)&Ks[row * 64 + (((4 + g) ^ c7) << 3)];
            f32x4 z = {};
            z = __builtin_amdgcn_mfma_f32_16x16x32_bf16(kf0, qf[0], z, 0, 0, 0);
            z = __builtin_amdgcn_mfma_f32_16x16x32_bf16(kf1, qf[1], z, 0, 0, 0);
            for (int r = 0; r < 4; ++r) t4[nt][r] = fmaf(z[r], sc2, nm2);
        }

        // per-lane max of 16 via max3 tree
        float ma = fmax3(t4[0][0], t4[0][1], t4[0][2]);
        float mb = fmax3(t4[0][3], t4[1][0], t4[1][1]);
        float mc = fmax3(t4[1][2], t4[1][3], t4[2][0]);
        float md = fmax3(t4[2][1], t4[2][2], t4[2][3]);
        float me = fmax3(t4[3][0], t4[3][1], t4[3][2]);
        float tm = fmax3(fmax3(ma, mb, mc), fmax3(md, me, t4[3][3]), -3.0e38f);
        if (!__all(tm <= THR)) {
            // rare: reduce max across the 4 g-groups (same q-row c)
            float pm = tm;
            pm = fmaxf(pm, __shfl_xor(pm, 16));
            pm = fmaxf(pm, __shfl_xor(pm, 32));
            float dm = fmaxf(pm, 0.f);
            nm2 -= dm;
            float alpha = exp2f(-dm);
            for (int nt = 0; nt < 4; ++nt)
                for (int r = 0; r < 4; ++r) t4[nt][r] -= dm;
            for (int r = 0; r < 4; ++r) {
                float ar = __shfl(alpha, 4 * g + r);
                for (int nd = 0; nd < 4; ++nd) o[nd][r] *= ar;
                lacc[r] *= ar;
            }
        }

        // p = 2^t, pack to mfma16 A-fragments
        bf16x4 pf[4];
        for (int nt = 0; nt < 4; ++nt) {
            float p0 = exp2f(t4[nt][0]), p1 = exp2f(t4[nt][1]);
            float p2 = exp2f(t4[nt][2]), p3 = exp2f(t4[nt][3]);
            union { unsigned u[2]; bf16x4 v; } pk;
            pk.u[0] = packbf2(p0, p1);
            pk.u[1] = packbf2(p2, p3);
            pf[nt] = pk.v;
        }

        // O += P V ; l += P * ones
        for (int nd = 0; nd < 4; ++nd) {
            int row = nd * 16 + c;
            for (int nt = 0; nt < 4; ++nt) {
                int off = row * 64 + (((2 * nt + (g >> 1)) ^ c7) << 3) + ((g & 1) << 2);
                bf16x4 vf = *(const bf16x4*)&Vs[off];
                o[nd] = mfma16(pf[nt], vf, o[nd]);
            }
        }
        for (int nt = 0; nt < 4; ++nt)
            lacc = mfma16(pf[nt], ones, lacc);
    }

    const int b = bh >> 3, h = bh & 7;
    for (int r = 0; r < 4; ++r) {
        float inv = 1.f / lacc[r];
        int m = b * 4096 + q0 + w * 16 + 4 * g + r;
        for (int nd = 0; nd < 4; ++nd) {
            int n = h * 64 + nd * 16 + c;
            Mo[(size_t)m * 512 + n] = f2bf(o[nd][r] * inv);
        }
    }
}

extern "C" void kernel_launch(void* const* d_in, const int* in_sizes, int n_in,
                              void* d_out, int out_size, void* d_ws, size_t ws_size,
                              hipStream_t stream) {
    const float* q  = (const float*)d_in[0];
    const float* Wq = (const float*)d_in[1];
    const float* bq = (const float*)d_in[2];
    const float* Wk = (const float*)d_in[3];
    const float* bk = (const float*)d_in[4];
    const float* Wv = (const float*)d_in[5];
    const float* bv = (const float*)d_in[6];
    const float* Wo = (const float*)d_in[7];
    const float* bo = (const float*)d_in[8];

    unsigned short* Qb = (unsigned short*)d_ws;            // 8 MB
    unsigned short* Kb = Qb + (size_t)16 * 4096 * 64;      // 8 MB
    unsigned short* Vt = Kb + (size_t)16 * 4096 * 64;      // 8 MB (V^T per head)
    unsigned short* Mg = Vt + (size_t)16 * 4096 * 64;      // merged bf16 [8192][512]

    dim3 gb(256);
    dim3 gqkv(64, 4, 3);
    gemm_qkv<<<gqkv, gb, 0, stream>>>(q, Wq, bq, Wk, bk, Wv, bv, Qb, Kb, Vt);

    dim3 ga(1024);
    attn64<<<ga, gb, 0, stream>>>(Qb, Kb, Vt, Mg);

    dim3 gg(64, 4);
    gemm_out<<<gg, gb, 0, stream>>>(Mg, Wo, bo, (float*)d_out);
}

// Round 8
// 197.702 us; speedup vs baseline: 1.7517x; 1.0082x over previous
//
#include <hip/hip_runtime.h>
#include <hip/hip_bf16.h>
#include <math.h>

typedef __attribute__((ext_vector_type(8))) short bf16x8;
typedef __attribute__((ext_vector_type(4))) short bf16x4;
typedef __attribute__((ext_vector_type(4))) float f32x4;

__device__ __forceinline__ unsigned short f2bf(float f) {
    union { float f; unsigned int u; } v; v.f = f;
    unsigned int u = v.u;
    u += 0x7fffu + ((u >> 16) & 1u);   // round-to-nearest-even
    return (unsigned short)(u >> 16);
}

__device__ __forceinline__ f32x4 mfma16(bf16x4 a, bf16x4 b, f32x4 c) {
#if __has_builtin(__builtin_amdgcn_mfma_f32_16x16x16bf16_1k)
    return __builtin_amdgcn_mfma_f32_16x16x16bf16_1k(a, b, c, 0, 0, 0);
#else
    asm volatile("v_mfma_f32_16x16x16_bf16 %0, %1, %2, %0\n\ts_nop 7"
                 : "+v"(c) : "v"(a), "v"(b));
    return c;
#endif
}

__device__ __forceinline__ unsigned packbf2(float a, float b) {
    __hip_bfloat162 h = __float22bfloat162_rn(float2{a, b});
    union { __hip_bfloat162 h; unsigned u; } v; v.h = h;
    return v.u;
}

__device__ __forceinline__ float fmax3(float a, float b, float c) {
    return fmaxf(fmaxf(a, b), c);   // clang fuses to v_max3_f32
}

// ---------------------------------------------------------------------------
// Shared GEMM body: C[m][n] = sum_k A[m][k] * W[n][k] + bias[n]
// M=8192, N=512, K=512. 128x128 tile, BK=32, 256 threads (4 waves 2x2).
// Loads for k-tile t+1 issue AFTER the second barrier (latency hides under
// the 16-MFMA compute phase instead of being drained at the barrier).
// ---------------------------------------------------------------------------
template<int A_BF16>
__device__ __forceinline__ void gemm_body(const void* Ap, const float* W,
                                          f32x4 (&acc)[4][4],
                                          unsigned short (*As)[40], unsigned short (*Bs)[40],
                                          int bm, int bn, int t)
{
    constexpr int Kdim = 512;
    const int lane = t & 63, g = lane >> 4, c = lane & 15;
    const int w = t >> 6, wr = w >> 1, wc = w & 1;

    uint4  paB[2];
    float4 paF[4];
    float4 pw[4];
    const int ccB = (t & 3) * 8, r0B = t >> 2;
    const int c4  = (t & 7) * 4, r0F = t >> 3;

    if (A_BF16) {
        const unsigned short* A = (const unsigned short*)Ap;
        for (int p = 0; p < 2; ++p)
            paB[p] = *(const uint4*)(A + (size_t)(bm + r0B + p * 64) * Kdim + ccB);
    } else {
        const float* A = (const float*)Ap;
        for (int p = 0; p < 4; ++p)
            paF[p] = *(const float4*)(A + (size_t)(bm + r0F + p * 32) * Kdim + c4);
    }
    for (int p = 0; p < 4; ++p)
        pw[p] = *(const float4*)(W + (size_t)(bn + r0F + p * 32) * Kdim + c4);

    for (int k0 = 0; k0 < Kdim; k0 += 32) {
        __syncthreads();
        if (A_BF16) {
            for (int p = 0; p < 2; ++p)
                *(uint4*)&As[r0B + p * 64][ccB] = paB[p];
        } else {
            for (int p = 0; p < 4; ++p) {
                float4 v = paF[p];
                ushort4 hv;
                hv.x = f2bf(v.x); hv.y = f2bf(v.y); hv.z = f2bf(v.z); hv.w = f2bf(v.w);
                *(ushort4*)&As[r0F + p * 32][c4] = hv;
            }
        }
        for (int p = 0; p < 4; ++p) {
            float4 v = pw[p];
            ushort4 hv;
            hv.x = f2bf(v.x); hv.y = f2bf(v.y); hv.z = f2bf(v.z); hv.w = f2bf(v.w);
            *(ushort4*)&Bs[r0F + p * 32][c4] = hv;
        }
        __syncthreads();
        if (k0 + 32 < Kdim) {
            const int kn = k0 + 32;
            if (A_BF16) {
                const unsigned short* A = (const unsigned short*)Ap;
                for (int p = 0; p < 2; ++p)
                    paB[p] = *(const uint4*)(A + (size_t)(bm + r0B + p * 64) * Kdim + kn + ccB);
            } else {
                const float* A = (const float*)Ap;
                for (int p = 0; p < 4; ++p)
                    paF[p] = *(const float4*)(A + (size_t)(bm + r0F + p * 32) * Kdim + kn + c4);
            }
            for (int p = 0; p < 4; ++p)
                pw[p] = *(const float4*)(W + (size_t)(bn + r0F + p * 32) * Kdim + kn + c4);
        }
        bf16x8 af[4], bfr[4];
        for (int i = 0; i < 4; ++i)
            af[i] = *(const bf16x8*)&As[wr * 64 + i * 16 + c][g * 8];
        for (int j = 0; j < 4; ++j)
            bfr[j] = *(const bf16x8*)&Bs[wc * 64 + j * 16 + c][g * 8];
        for (int i = 0; i < 4; ++i)
            for (int j = 0; j < 4; ++j)
                acc[i][j] = __builtin_amdgcn_mfma_f32_16x16x32_bf16(af[i], bfr[j], acc[i][j], 0, 0, 0);
    }
}

// Fused Q/K/V projections: blockIdx.z selects weight set. q fp32 input.
__global__ __launch_bounds__(256, 2)
void gemm_qkv(const float* __restrict__ q,
              const float* __restrict__ Wq, const float* __restrict__ bq,
              const float* __restrict__ Wk, const float* __restrict__ bk,
              const float* __restrict__ Wv, const float* __restrict__ bv,
              unsigned short* __restrict__ Qo, unsigned short* __restrict__ Ko,
              unsigned short* __restrict__ Vo)
{
    __shared__ unsigned short As[128][40];
    __shared__ unsigned short Bs[128][40];
    const int t = threadIdx.x, z = blockIdx.z;
    const int lane = t & 63, g = lane >> 4, c = lane & 15;
    const int w = t >> 6, wr = w >> 1, wc = w & 1;
    const int bm = blockIdx.x * 128, bn = blockIdx.y * 128;

    const float* W    = (z == 0) ? Wq : (z == 1) ? Wk : Wv;
    const float* bias = (z == 0) ? bq : (z == 1) ? bk : bv;
    unsigned short* Out = (z == 0) ? Qo : (z == 1) ? Ko : Vo;

    f32x4 acc[4][4] = {};
    gemm_body<0>((const void*)q, W, acc, As, Bs, bm, bn, t);

    float bv4[4];
    for (int j = 0; j < 4; ++j) bv4[j] = bias[bn + wc * 64 + j * 16 + c];
    for (int i = 0; i < 4; ++i)
        for (int j = 0; j < 4; ++j)
            for (int r = 0; r < 4; ++r) {
                int m = bm + wr * 64 + i * 16 + 4 * g + r;
                int n = bn + wc * 64 + j * 16 + c;
                float val = acc[i][j][r] + bv4[j];
                int b = m >> 12, s = m & 4095, h = n >> 6, d = n & 63;
                if (z < 2)
                    Out[((((size_t)b * 8 + h) * 4096 + s) << 6) + d] = f2bf(val);
                else
                    Out[(((size_t)b * 8 + h) * 64 + d) * 4096 + s] = f2bf(val);
            }
}

// Output projection: A bf16 [8192][512], out fp32 [8192][512].
__global__ __launch_bounds__(256, 2)
void gemm_out(const unsigned short* __restrict__ A, const float* __restrict__ W,
              const float* __restrict__ bias, float* __restrict__ Out)
{
    __shared__ unsigned short As[128][40];
    __shared__ unsigned short Bs[128][40];
    const int t = threadIdx.x;
    const int lane = t & 63, g = lane >> 4, c = lane & 15;
    const int w = t >> 6, wr = w >> 1, wc = w & 1;
    const int bm = blockIdx.x * 128, bn = blockIdx.y * 128;

    f32x4 acc[4][4] = {};
    gemm_body<1>((const void*)A, W, acc, As, Bs, bm, bn, t);

    float bv4[4];
    for (int j = 0; j < 4; ++j) bv4[j] = bias[bn + wc * 64 + j * 16 + c];
    for (int i = 0; i < 4; ++i)
        for (int j = 0; j < 4; ++j)
            for (int r = 0; r < 4; ++r) {
                int m = bm + wr * 64 + i * 16 + 4 * g + r;
                int n = bn + wc * 64 + j * 16 + c;
                Out[(size_t)m * 512 + n] = acc[i][j][r] + bv4[j];
            }
}

// ---------------------------------------------------------------------------
// Flash attention fwd. Q,K: [16][4096][64] bf16; VT: [16][64][4096] bf16.
// 4 waves, 128 Q-rows/block (TWO 16-row groups per wave), KV-tile 64.
// Same staging + LDS reads as the 64-row version, but every K/V fragment
// read now feeds TWO MFMAs (q-groups a,b) -> per-work overhead halves.
// Conflict-free swizzled LDS (stride 64, slot ^= row&7 both sides).
// Swapped QK^T; per-lane softmax; l via ones-column MFMA; XCD swizzle.
// ---------------------------------------------------------------------------
__global__ __launch_bounds__(256, 2)
void attn128(const unsigned short* __restrict__ Q, const unsigned short* __restrict__ Kh,
             const unsigned short* __restrict__ VT, unsigned short* __restrict__ Mo)
{
    __shared__ unsigned short Ks[64 * 64];   // [key][d], swizzled slots
    __shared__ unsigned short Vs[64 * 64];   // [d][key], swizzled slots

    const int t = threadIdx.x, w = t >> 6, lane = t & 63, g = lane >> 4, c = lane & 15;
    // XCD-aware swizzle: 512 blocks, 8 XCDs, bijective (512%8==0).
    const int idp = (blockIdx.x & 7) * 64 + (blockIdx.x >> 3);
    const int bh = idp >> 5;
    const int q0 = (idp & 31) * 128;
    const unsigned short* Qb = Q + (size_t)bh * 4096 * 64;
    const unsigned short* Kb = Kh + (size_t)bh * 4096 * 64;
    const unsigned short* Vb = VT + (size_t)bh * 64 * 4096;

    // two q-groups per wave: rows w*32+c (a) and w*32+16+c (b)
    bf16x8 qfa0, qfa1, qfb0, qfb1;
    {
        int qra = q0 + w * 32 + c;
        qfa0 = *(const bf16x8*)(Qb + (size_t)qra * 64 + g * 8);
        qfa1 = *(const bf16x8*)(Qb + (size_t)qra * 64 + 32 + g * 8);
        qfb0 = *(const bf16x8*)(Qb + (size_t)(qra + 16) * 64 + g * 8);
        qfb1 = *(const bf16x8*)(Qb + (size_t)(qra + 16) * 64 + 32 + g * 8);
    }

    f32x4 oa[4] = {}, ob[4] = {};   // o*[nd][r] = O[row 4g+r][d = nd*16+c]
    f32x4 lacca = {}, laccb = {};
    float nma = 0.f, nmb = 0.f;     // -m (exp2 domain) per lane's q-row

    bf16x4 ones;
    ones[0] = ones[1] = ones[2] = ones[3] = (short)0x3F80;   // bf16 1.0

    // staging: row = t>>2 (64 rows), 2 swizzled 16B slots per thread
    const int srow = t >> 2, scol = (t & 3) * 16;
    const int s0 = (t & 3) * 2, r7 = srow & 7;
    const int woff0 = srow * 64 + ((s0 ^ r7) << 3);
    const int woff1 = srow * 64 + (((s0 + 1) ^ r7) << 3);
    const unsigned short* kp0 = Kb + (size_t)srow * 64 + scol;
    const unsigned short* vp0 = Vb + (size_t)srow * 4096 + scol;

    uint4 ka0 = *(const uint4*)(kp0);
    uint4 ka1 = *(const uint4*)(kp0 + 8);
    uint4 va0 = *(const uint4*)(vp0);
    uint4 va1 = *(const uint4*)(vp0 + 8);

    const float sc2 = 0.125f * 1.44269504f;   // scale * log2(e)
    const float THR = 10.f;                   // p bounded by 2^10
    const int c7 = c & 7;

    for (int jt = 0; jt < 64; ++jt) {
        __syncthreads();
        *(uint4*)&Ks[woff0] = ka0;
        *(uint4*)&Ks[woff1] = ka1;
        *(uint4*)&Vs[woff0] = va0;
        *(uint4*)&Vs[woff1] = va1;
        __syncthreads();
        // next tile's loads issue after the barrier: fly across compute
        if (jt < 63) {
            const unsigned short* kp = kp0 + (size_t)(jt + 1) * 4096;
            ka0 = *(const uint4*)(kp);
            ka1 = *(const uint4*)(kp + 8);
            const unsigned short* vp = vp0 + (jt + 1) * 64;
            va0 = *(const uint4*)(vp);
            va1 = *(const uint4*)(vp + 8);
        }

        // S^T = K Q^T for both q-groups; each kf read feeds 2 MFMAs
        f32x4 ta[4], tb[4];
        #pragma unroll
        for (int nt = 0; nt < 4; ++nt) {
            int row = nt * 16 + c;
            bf16x8 kf0 = *(const bf16x8*)&Ks[row * 64 + ((g ^ c7) << 3)];
            bf16x8 kf1 = *(const bf16x8*)&Ks[row * 64 + (((4 + g) ^ c7) << 3)];
            f32x4 za = {}, zb = {};
            za = __builtin_amdgcn_mfma_f32_16x16x32_bf16(kf0, qfa0, za, 0, 0, 0);
            za = __builtin_amdgcn_mfma_f32_16x16x32_bf16(kf1, qfa1, za, 0, 0, 0);
            zb = __builtin_amdgcn_mfma_f32_16x16x32_bf16(kf0, qfb0, zb, 0, 0, 0);
            zb = __builtin_amdgcn_mfma_f32_16x16x32_bf16(kf1, qfb1, zb, 0, 0, 0);
            #pragma unroll
            for (int r = 0; r < 4; ++r) {
                ta[nt][r] = fmaf(za[r], sc2, nma);
                tb[nt][r] = fmaf(zb[r], sc2, nmb);
            }
        }

        // per-lane max via max3 trees
        float tma = fmax3(fmax3(fmax3(ta[0][0], ta[0][1], ta[0][2]),
                                fmax3(ta[0][3], ta[1][0], ta[1][1]),
                                fmax3(ta[1][2], ta[1][3], ta[2][0])),
                          fmax3(fmax3(ta[2][1], ta[2][2], ta[2][3]),
                                fmax3(ta[3][0], ta[3][1], ta[3][2]), ta[3][3]),
                          -3.0e38f);
        float tmb = fmax3(fmax3(fmax3(tb[0][0], tb[0][1], tb[0][2]),
                                fmax3(tb[0][3], tb[1][0], tb[1][1]),
                                fmax3(tb[1][2], tb[1][3], tb[2][0])),
                          fmax3(fmax3(tb[2][1], tb[2][2], tb[2][3]),
                                fmax3(tb[3][0], tb[3][1], tb[3][2]), tb[3][3]),
                          -3.0e38f);
        if (!__all(tma <= THR && tmb <= THR)) {
            // rare: rescale both q-groups
            float pma = tma, pmb = tmb;
            pma = fmaxf(pma, __shfl_xor(pma, 16));
            pma = fmaxf(pma, __shfl_xor(pma, 32));
            pmb = fmaxf(pmb, __shfl_xor(pmb, 16));
            pmb = fmaxf(pmb, __shfl_xor(pmb, 32));
            float dma = fmaxf(pma, 0.f), dmb = fmaxf(pmb, 0.f);
            nma -= dma; nmb -= dmb;
            float ala = exp2f(-dma), alb = exp2f(-dmb);
            #pragma unroll
            for (int nt = 0; nt < 4; ++nt)
                #pragma unroll
                for (int r = 0; r < 4; ++r) { ta[nt][r] -= dma; tb[nt][r] -= dmb; }
            #pragma unroll
            for (int r = 0; r < 4; ++r) {
                float ara = __shfl(ala, 4 * g + r);
                float arb = __shfl(alb, 4 * g + r);
                #pragma unroll
                for (int nd = 0; nd < 4; ++nd) { oa[nd][r] *= ara; ob[nd][r] *= arb; }
                lacca[r] *= ara; laccb[r] *= arb;
            }
        }

        // p = 2^t -> bf16 A-fragments for both groups
        bf16x4 pfa[4], pfb[4];
        #pragma unroll
        for (int nt = 0; nt < 4; ++nt) {
            union { unsigned u[2]; bf16x4 v; } pk;
            pk.u[0] = packbf2(exp2f(ta[nt][0]), exp2f(ta[nt][1]));
            pk.u[1] = packbf2(exp2f(ta[nt][2]), exp2f(ta[nt][3]));
            pfa[nt] = pk.v;
            pk.u[0] = packbf2(exp2f(tb[nt][0]), exp2f(tb[nt][1]));
            pk.u[1] = packbf2(exp2f(tb[nt][2]), exp2f(tb[nt][3]));
            pfb[nt] = pk.v;
        }

        // O += P V for both groups; each vf read feeds 2 MFMAs
        #pragma unroll
        for (int nd = 0; nd < 4; ++nd) {
            int row = nd * 16 + c;
            #pragma unroll
            for (int nt = 0; nt < 4; ++nt) {
                int off = row * 64 + (((2 * nt + (g >> 1)) ^ c7) << 3) + ((g & 1) << 2);
                bf16x4 vf = *(const bf16x4*)&Vs[off];
                oa[nd] = mfma16(pfa[nt], vf, oa[nd]);
                ob[nd] = mfma16(pfb[nt], vf, ob[nd]);
            }
        }
        #pragma unroll
        for (int nt = 0; nt < 4; ++nt) {
            lacca = mfma16(pfa[nt], ones, lacca);
            laccb = mfma16(pfb[nt], ones, laccb);
        }
    }

    const int b = bh >> 3, h = bh & 7;
    #pragma unroll
    for (int r = 0; r < 4; ++r) {
        float inva = 1.f / lacca[r];
        float invb = 1.f / laccb[r];
        int ma = b * 4096 + q0 + w * 32 + 4 * g + r;
        #pragma unroll
        for (int nd = 0; nd < 4; ++nd) {
            int n = h * 64 + nd * 16 + c;
            Mo[(size_t)ma * 512 + n]        = f2bf(oa[nd][r] * inva);
            Mo[(size_t)(ma + 16) * 512 + n] = f2bf(ob[nd][r] * invb);
        }
    }
}

extern "C" void kernel_launch(void* const* d_in, const int* in_sizes, int n_in,
                              void* d_out, int out_size, void* d_ws, size_t ws_size,
                              hipStream_t stream) {
    const float* q  = (const float*)d_in[0];
    const float* Wq = (const float*)d_in[1];
    const float* bq = (const float*)d_in[2];
    const float* Wk = (const float*)d_in[3];
    const float* bk = (const float*)d_in[4];
    const float* Wv = (const float*)d_in[5];
    const float* bv = (const float*)d_in[6];
    const float* Wo = (const float*)d_in[7];
    const float* bo = (const float*)d_in[8];

    unsigned short* Qb = (unsigned short*)d_ws;            // 8 MB
    unsigned short* Kb = Qb + (size_t)16 * 4096 * 64;      // 8 MB
    unsigned short* Vt = Kb + (size_t)16 * 4096 * 64;      // 8 MB (V^T per head)
    unsigned short* Mg = Vt + (size_t)16 * 4096 * 64;      // merged bf16 [8192][512]

    dim3 gb(256);
    dim3 gqkv(64, 4, 3);
    gemm_qkv<<<gqkv, gb, 0, stream>>>(q, Wq, bq, Wk, bk, Wv, bv, Qb, Kb, Vt);

    dim3 ga(512);
    attn128<<<ga, gb, 0, stream>>>(Qb, Kb, Vt, Mg);

    dim3 gg(64, 4);
    gemm_out<<<gg, gb, 0, stream>>>(Mg, Wo, bo, (float*)d_out);
}

// Round 9
// 184.055 us; speedup vs baseline: 1.8816x; 1.0741x over previous
//
#include <hip/hip_runtime.h>
#include <hip/hip_bf16.h>
#include <math.h>

typedef __attribute__((ext_vector_type(8))) short bf16x8;
typedef __attribute__((ext_vector_type(4))) short bf16x4;
typedef __attribute__((ext_vector_type(4))) float f32x4;

__device__ __forceinline__ unsigned short f2bf(float f) {
    union { float f; unsigned int u; } v; v.f = f;
    unsigned int u = v.u;
    u += 0x7fffu + ((u >> 16) & 1u);   // round-to-nearest-even
    return (unsigned short)(u >> 16);
}

__device__ __forceinline__ f32x4 mfma16(bf16x4 a, bf16x4 b, f32x4 c) {
#if __has_builtin(__builtin_amdgcn_mfma_f32_16x16x16bf16_1k)
    return __builtin_amdgcn_mfma_f32_16x16x16bf16_1k(a, b, c, 0, 0, 0);
#else
    asm volatile("v_mfma_f32_16x16x16_bf16 %0, %1, %2, %0\n\ts_nop 7"
                 : "+v"(c) : "v"(a), "v"(b));
    return c;
#endif
}

__device__ __forceinline__ unsigned packbf2(float a, float b) {
    __hip_bfloat162 h = __float22bfloat162_rn(float2{a, b});
    union { __hip_bfloat162 h; unsigned u; } v; v.h = h;
    return v.u;
}

__device__ __forceinline__ float fmax3(float a, float b, float c) {
    return fmaxf(fmaxf(a, b), c);   // clang fuses to v_max3_f32
}

// ---------------------------------------------------------------------------
// Shared GEMM body: C[m][n] = sum_k A[m][k] * W[n][k] + bias[n]
// M=8192, N=512, K=512. 128x128 tile, BK=32, 256 threads (4 waves 2x2).
// ---------------------------------------------------------------------------
template<int A_BF16>
__device__ __forceinline__ void gemm_body(const void* Ap, const float* W,
                                          f32x4 (&acc)[4][4],
                                          unsigned short (*As)[40], unsigned short (*Bs)[40],
                                          int bm, int bn, int t)
{
    constexpr int Kdim = 512;
    const int lane = t & 63, g = lane >> 4, c = lane & 15;
    const int w = t >> 6, wr = w >> 1, wc = w & 1;

    uint4  paB[2];
    float4 paF[4];
    float4 pw[4];
    const int ccB = (t & 3) * 8, r0B = t >> 2;
    const int c4  = (t & 7) * 4, r0F = t >> 3;

    if (A_BF16) {
        const unsigned short* A = (const unsigned short*)Ap;
        for (int p = 0; p < 2; ++p)
            paB[p] = *(const uint4*)(A + (size_t)(bm + r0B + p * 64) * Kdim + ccB);
    } else {
        const float* A = (const float*)Ap;
        for (int p = 0; p < 4; ++p)
            paF[p] = *(const float4*)(A + (size_t)(bm + r0F + p * 32) * Kdim + c4);
    }
    for (int p = 0; p < 4; ++p)
        pw[p] = *(const float4*)(W + (size_t)(bn + r0F + p * 32) * Kdim + c4);

    for (int k0 = 0; k0 < Kdim; k0 += 32) {
        __syncthreads();
        if (A_BF16) {
            for (int p = 0; p < 2; ++p)
                *(uint4*)&As[r0B + p * 64][ccB] = paB[p];
        } else {
            for (int p = 0; p < 4; ++p) {
                float4 v = paF[p];
                ushort4 hv;
                hv.x = f2bf(v.x); hv.y = f2bf(v.y); hv.z = f2bf(v.z); hv.w = f2bf(v.w);
                *(ushort4*)&As[r0F + p * 32][c4] = hv;
            }
        }
        for (int p = 0; p < 4; ++p) {
            float4 v = pw[p];
            ushort4 hv;
            hv.x = f2bf(v.x); hv.y = f2bf(v.y); hv.z = f2bf(v.z); hv.w = f2bf(v.w);
            *(ushort4*)&Bs[r0F + p * 32][c4] = hv;
        }
        __syncthreads();
        if (k0 + 32 < Kdim) {
            const int kn = k0 + 32;
            if (A_BF16) {
                const unsigned short* A = (const unsigned short*)Ap;
                for (int p = 0; p < 2; ++p)
                    paB[p] = *(const uint4*)(A + (size_t)(bm + r0B + p * 64) * Kdim + kn + ccB);
            } else {
                const float* A = (const float*)Ap;
                for (int p = 0; p < 4; ++p)
                    paF[p] = *(const float4*)(A + (size_t)(bm + r0F + p * 32) * Kdim + kn + c4);
            }
            for (int p = 0; p < 4; ++p)
                pw[p] = *(const float4*)(W + (size_t)(bn + r0F + p * 32) * Kdim + kn + c4);
        }
        bf16x8 af[4], bfr[4];
        for (int i = 0; i < 4; ++i)
            af[i] = *(const bf16x8*)&As[wr * 64 + i * 16 + c][g * 8];
        for (int j = 0; j < 4; ++j)
            bfr[j] = *(const bf16x8*)&Bs[wc * 64 + j * 16 + c][g * 8];
        for (int i = 0; i < 4; ++i)
            for (int j = 0; j < 4; ++j)
                acc[i][j] = __builtin_amdgcn_mfma_f32_16x16x32_bf16(af[i], bfr[j], acc[i][j], 0, 0, 0);
    }
}

// Fused Q/K/V projections: blockIdx.z selects weight set. q fp32 input.
// Q output is PRE-SCALED by 0.125*log2(e) so attention needs no per-element
// scale (folded into the QK^T MFMA via its C operand).
__global__ __launch_bounds__(256, 2)
void gemm_qkv(const float* __restrict__ q,
              const float* __restrict__ Wq, const float* __restrict__ bq,
              const float* __restrict__ Wk, const float* __restrict__ bk,
              const float* __restrict__ Wv, const float* __restrict__ bv,
              unsigned short* __restrict__ Qo, unsigned short* __restrict__ Ko,
              unsigned short* __restrict__ Vo)
{
    __shared__ unsigned short As[128][40];
    __shared__ unsigned short Bs[128][40];
    const int t = threadIdx.x, z = blockIdx.z;
    const int lane = t & 63, g = lane >> 4, c = lane & 15;
    const int w = t >> 6, wr = w >> 1, wc = w & 1;
    const int bm = blockIdx.x * 128, bn = blockIdx.y * 128;

    const float* W    = (z == 0) ? Wq : (z == 1) ? Wk : Wv;
    const float* bias = (z == 0) ? bq : (z == 1) ? bk : bv;
    unsigned short* Out = (z == 0) ? Qo : (z == 1) ? Ko : Vo;
    const float osc = (z == 0) ? 0.125f * 1.44269504f : 1.0f;

    f32x4 acc[4][4] = {};
    gemm_body<0>((const void*)q, W, acc, As, Bs, bm, bn, t);

    float bv4[4];
    for (int j = 0; j < 4; ++j) bv4[j] = bias[bn + wc * 64 + j * 16 + c];
    for (int i = 0; i < 4; ++i)
        for (int j = 0; j < 4; ++j)
            for (int r = 0; r < 4; ++r) {
                int m = bm + wr * 64 + i * 16 + 4 * g + r;
                int n = bn + wc * 64 + j * 16 + c;
                float val = (acc[i][j][r] + bv4[j]) * osc;
                int b = m >> 12, s = m & 4095, h = n >> 6, d = n & 63;
                if (z < 2)
                    Out[((((size_t)b * 8 + h) * 4096 + s) << 6) + d] = f2bf(val);
                else
                    Out[(((size_t)b * 8 + h) * 64 + d) * 4096 + s] = f2bf(val);
            }
}

// Output projection: A bf16 [8192][512], out fp32 [8192][512].
__global__ __launch_bounds__(256, 2)
void gemm_out(const unsigned short* __restrict__ A, const float* __restrict__ W,
              const float* __restrict__ bias, float* __restrict__ Out)
{
    __shared__ unsigned short As[128][40];
    __shared__ unsigned short Bs[128][40];
    const int t = threadIdx.x;
    const int lane = t & 63, g = lane >> 4, c = lane & 15;
    const int w = t >> 6, wr = w >> 1, wc = w & 1;
    const int bm = blockIdx.x * 128, bn = blockIdx.y * 128;

    f32x4 acc[4][4] = {};
    gemm_body<1>((const void*)A, W, acc, As, Bs, bm, bn, t);

    float bv4[4];
    for (int j = 0; j < 4; ++j) bv4[j] = bias[bn + wc * 64 + j * 16 + c];
    for (int i = 0; i < 4; ++i)
        for (int j = 0; j < 4; ++j)
            for (int r = 0; r < 4; ++r) {
                int m = bm + wr * 64 + i * 16 + 4 * g + r;
                int n = bn + wc * 64 + j * 16 + c;
                Out[(size_t)m * 512 + n] = acc[i][j][r] + bv4[j];
            }
}

// ---------------------------------------------------------------------------
// Flash attention fwd. Q(pre-scaled),K: [16][4096][64] bf16; VT: [16][64][4096].
// 4 waves, 128 Q-rows/block (two 16-row groups/wave), KV-tile 64.
// DOUBLE-BUFFERED LDS -> ONE barrier per tile. Loads for t+1 issue right
// after the barrier (span the compute phase); ds_writes land at iter end.
// QK^T accumulator is C-initialized with -m (Q pre-scaled) -> no per-element
// fmaf. Conflict-free swizzled LDS (stride 64, slot^=(row&7) both sides).
// Swapped QK^T; per-lane softmax; l via ones-column MFMA; XCD swizzle.
// ---------------------------------------------------------------------------
__global__ __launch_bounds__(256, 2)
void attn128(const unsigned short* __restrict__ Q, const unsigned short* __restrict__ Kh,
             const unsigned short* __restrict__ VT, unsigned short* __restrict__ Mo)
{
    __shared__ unsigned short Ks[2 * 64 * 64];   // double-buffered, swizzled
    __shared__ unsigned short Vs[2 * 64 * 64];

    const int t = threadIdx.x, w = t >> 6, lane = t & 63, g = lane >> 4, c = lane & 15;
    // XCD-aware swizzle: 512 blocks, 8 XCDs, bijective (512%8==0).
    const int idp = (blockIdx.x & 7) * 64 + (blockIdx.x >> 3);
    const int bh = idp >> 5;
    const int q0 = (idp & 31) * 128;
    const unsigned short* Qb = Q + (size_t)bh * 4096 * 64;
    const unsigned short* Kb = Kh + (size_t)bh * 4096 * 64;
    const unsigned short* Vb = VT + (size_t)bh * 64 * 4096;

    // two q-groups per wave: rows w*32+c (a) and w*32+16+c (b)
    bf16x8 qfa0, qfa1, qfb0, qfb1;
    {
        int qra = q0 + w * 32 + c;
        qfa0 = *(const bf16x8*)(Qb + (size_t)qra * 64 + g * 8);
        qfa1 = *(const bf16x8*)(Qb + (size_t)qra * 64 + 32 + g * 8);
        qfb0 = *(const bf16x8*)(Qb + (size_t)(qra + 16) * 64 + g * 8);
        qfb1 = *(const bf16x8*)(Qb + (size_t)(qra + 16) * 64 + 32 + g * 8);
    }

    f32x4 oa[4] = {}, ob[4] = {};   // o*[nd][r] = O[row 4g+r][d = nd*16+c]
    f32x4 lacca = {}, laccb = {};
    float nma = 0.f, nmb = 0.f;     // -m (exp2 domain) per lane's q-row

    bf16x4 ones;
    ones[0] = ones[1] = ones[2] = ones[3] = (short)0x3F80;   // bf16 1.0

    // staging: row = t>>2 (64 rows), 2 swizzled 16B slots per thread
    const int srow = t >> 2, scol = (t & 3) * 16;
    const int s0 = (t & 3) * 2, r7 = srow & 7;
    const int woff0 = srow * 64 + ((s0 ^ r7) << 3);
    const int woff1 = srow * 64 + (((s0 + 1) ^ r7) << 3);
    const unsigned short* kp0 = Kb + (size_t)srow * 64 + scol;
    const unsigned short* vp0 = Vb + (size_t)srow * 4096 + scol;

    uint4 ka0 = *(const uint4*)(kp0);
    uint4 ka1 = *(const uint4*)(kp0 + 8);
    uint4 va0 = *(const uint4*)(vp0);
    uint4 va1 = *(const uint4*)(vp0 + 8);
    // prologue: stage tile 0 into buffer 0
    *(uint4*)&Ks[woff0] = ka0;
    *(uint4*)&Ks[woff1] = ka1;
    *(uint4*)&Vs[woff0] = va0;
    *(uint4*)&Vs[woff1] = va1;

    const float THR = 10.f;                   // p bounded by 2^10
    const int c7 = c & 7;

    auto tile_iter = [&](int jt, const unsigned short* Kc, const unsigned short* Vc,
                         unsigned short* Kn, unsigned short* Vn) {
        __syncthreads();
        // issue next tile's loads right after the barrier: span compute phase
        if (jt < 63) {
            const unsigned short* kp = kp0 + (size_t)(jt + 1) * 4096;
            ka0 = *(const uint4*)(kp);
            ka1 = *(const uint4*)(kp + 8);
            const unsigned short* vp = vp0 + (jt + 1) * 64;
            va0 = *(const uint4*)(vp);
            va1 = *(const uint4*)(vp + 8);
        }

        // S^T = K Q^T, accumulator C-initialized with -m (Q pre-scaled)
        f32x4 ta[4], tb[4];
        #pragma unroll
        for (int nt = 0; nt < 4; ++nt) {
            int row = nt * 16 + c;
            bf16x8 kf0 = *(const bf16x8*)&Kc[row * 64 + ((g ^ c7) << 3)];
            bf16x8 kf1 = *(const bf16x8*)&Kc[row * 64 + (((4 + g) ^ c7) << 3)];
            f32x4 za = {nma, nma, nma, nma};
            f32x4 zb = {nmb, nmb, nmb, nmb};
            za = __builtin_amdgcn_mfma_f32_16x16x32_bf16(kf0, qfa0, za, 0, 0, 0);
            za = __builtin_amdgcn_mfma_f32_16x16x32_bf16(kf1, qfa1, za, 0, 0, 0);
            zb = __builtin_amdgcn_mfma_f32_16x16x32_bf16(kf0, qfb0, zb, 0, 0, 0);
            zb = __builtin_amdgcn_mfma_f32_16x16x32_bf16(kf1, qfb1, zb, 0, 0, 0);
            ta[nt] = za;
            tb[nt] = zb;
        }

        // per-lane max via max3 trees
        float tma = fmax3(fmax3(fmax3(ta[0][0], ta[0][1], ta[0][2]),
                                fmax3(ta[0][3], ta[1][0], ta[1][1]),
                                fmax3(ta[1][2], ta[1][3], ta[2][0])),
                          fmax3(ta[2][1], ta[2][2], ta[2][3]),
                          fmax3(fmax3(ta[3][0], ta[3][1], ta[3][2]), ta[3][3], ta[3][3]));
        float tmb = fmax3(fmax3(fmax3(tb[0][0], tb[0][1], tb[0][2]),
                                fmax3(tb[0][3], tb[1][0], tb[1][1]),
                                fmax3(tb[1][2], tb[1][3], tb[2][0])),
                          fmax3(tb[2][1], tb[2][2], tb[2][3]),
                          fmax3(fmax3(tb[3][0], tb[3][1], tb[3][2]), tb[3][3], tb[3][3]));
        if (!__all(tma <= THR && tmb <= THR)) {
            // rare: rescale both q-groups
            float pma = tma, pmb = tmb;
            pma = fmaxf(pma, __shfl_xor(pma, 16));
            pma = fmaxf(pma, __shfl_xor(pma, 32));
            pmb = fmaxf(pmb, __shfl_xor(pmb, 16));
            pmb = fmaxf(pmb, __shfl_xor(pmb, 32));
            float dma = fmaxf(pma, 0.f), dmb = fmaxf(pmb, 0.f);
            nma -= dma; nmb -= dmb;
            float ala = exp2f(-dma), alb = exp2f(-dmb);
            #pragma unroll
            for (int nt = 0; nt < 4; ++nt)
                #pragma unroll
                for (int r = 0; r < 4; ++r) { ta[nt][r] -= dma; tb[nt][r] -= dmb; }
            #pragma unroll
            for (int r = 0; r < 4; ++r) {
                float ara = __shfl(ala, 4 * g + r);
                float arb = __shfl(alb, 4 * g + r);
                #pragma unroll
                for (int nd = 0; nd < 4; ++nd) { oa[nd][r] *= ara; ob[nd][r] *= arb; }
                lacca[r] *= ara; laccb[r] *= arb;
            }
        }

        // p = 2^t -> bf16 A-fragments for both groups
        bf16x4 pfa[4], pfb[4];
        #pragma unroll
        for (int nt = 0; nt < 4; ++nt) {
            union { unsigned u[2]; bf16x4 v; } pk;
            pk.u[0] = packbf2(exp2f(ta[nt][0]), exp2f(ta[nt][1]));
            pk.u[1] = packbf2(exp2f(ta[nt][2]), exp2f(ta[nt][3]));
            pfa[nt] = pk.v;
            pk.u[0] = packbf2(exp2f(tb[nt][0]), exp2f(tb[nt][1]));
            pk.u[1] = packbf2(exp2f(tb[nt][2]), exp2f(tb[nt][3]));
            pfb[nt] = pk.v;
        }

        // O += P V for both groups; each vf read feeds 2 MFMAs
        #pragma unroll
        for (int nd = 0; nd < 4; ++nd) {
            int row = nd * 16 + c;
            #pragma unroll
            for (int nt = 0; nt < 4; ++nt) {
                int off = row * 64 + (((2 * nt + (g >> 1)) ^ c7) << 3) + ((g & 1) << 2);
                bf16x4 vf = *(const bf16x4*)&Vc[off];
                oa[nd] = mfma16(pfa[nt], vf, oa[nd]);
                ob[nd] = mfma16(pfb[nt], vf, ob[nd]);
            }
        }
        #pragma unroll
        for (int nt = 0; nt < 4; ++nt) {
            lacca = mfma16(pfa[nt], ones, lacca);
            laccb = mfma16(pfb[nt], ones, laccb);
        }

        // stage tile jt+1 into the other buffer (waits on this iter's loads;
        // latency was hidden under the compute above)
        if (jt < 63) {
            *(uint4*)&Kn[woff0] = ka0;
            *(uint4*)&Kn[woff1] = ka1;
            *(uint4*)&Vn[woff0] = va0;
            *(uint4*)&Vn[woff1] = va1;
        }
    };

    for (int jt2 = 0; jt2 < 64; jt2 += 2) {
        tile_iter(jt2,     &Ks[0],    &Vs[0],    &Ks[4096], &Vs[4096]);
        tile_iter(jt2 + 1, &Ks[4096], &Vs[4096], &Ks[0],    &Vs[0]);
    }

    const int b = bh >> 3, h = bh & 7;
    #pragma unroll
    for (int r = 0; r < 4; ++r) {
        float inva = 1.f / lacca[r];
        float invb = 1.f / laccb[r];
        int ma = b * 4096 + q0 + w * 32 + 4 * g + r;
        #pragma unroll
        for (int nd = 0; nd < 4; ++nd) {
            int n = h * 64 + nd * 16 + c;
            Mo[(size_t)ma * 512 + n]        = f2bf(oa[nd][r] * inva);
            Mo[(size_t)(ma + 16) * 512 + n] = f2bf(ob[nd][r] * invb);
        }
    }
}

extern "C" void kernel_launch(void* const* d_in, const int* in_sizes, int n_in,
                              void* d_out, int out_size, void* d_ws, size_t ws_size,
                              hipStream_t stream) {
    const float* q  = (const float*)d_in[0];
    const float* Wq = (const float*)d_in[1];
    const float* bq = (const float*)d_in[2];
    const float* Wk = (const float*)d_in[3];
    const float* bk = (const float*)d_in[4];
    const float* Wv = (const float*)d_in[5];
    const float* bv = (const float*)d_in[6];
    const float* Wo = (const float*)d_in[7];
    const float* bo = (const float*)d_in[8];

    unsigned short* Qb = (unsigned short*)d_ws;            // 8 MB
    unsigned short* Kb = Qb + (size_t)16 * 4096 * 64;      // 8 MB
    unsigned short* Vt = Kb + (size_t)16 * 4096 * 64;      // 8 MB (V^T per head)
    unsigned short* Mg = Vt + (size_t)16 * 4096 * 64;      // merged bf16 [8192][512]

    dim3 gb(256);
    dim3 gqkv(64, 4, 3);
    gemm_qkv<<<gqkv, gb, 0, stream>>>(q, Wq, bq, Wk, bk, Wv, bv, Qb, Kb, Vt);

    dim3 ga(512);
    attn128<<<ga, gb, 0, stream>>>(Qb, Kb, Vt, Mg);

    dim3 gg(64, 4);
    gemm_out<<<gg, gb, 0, stream>>>(Mg, Wo, bo, (float*)d_out);
}

// Round 10
// 181.928 us; speedup vs baseline: 1.9036x; 1.0117x over previous
//
#include <hip/hip_runtime.h>
#include <hip/hip_bf16.h>
#include <math.h>

typedef __attribute__((ext_vector_type(8))) short bf16x8;
typedef __attribute__((ext_vector_type(4))) short bf16x4;
typedef __attribute__((ext_vector_type(4))) float f32x4;

__device__ __forceinline__ unsigned short f2bf(float f) {
    union { float f; unsigned int u; } v; v.f = f;
    unsigned int u = v.u;
    u += 0x7fffu + ((u >> 16) & 1u);   // round-to-nearest-even
    return (unsigned short)(u >> 16);
}

__device__ __forceinline__ f32x4 mfma16(bf16x4 a, bf16x4 b, f32x4 c) {
#if __has_builtin(__builtin_amdgcn_mfma_f32_16x16x16bf16_1k)
    return __builtin_amdgcn_mfma_f32_16x16x16bf16_1k(a, b, c, 0, 0, 0);
#else
    asm volatile("v_mfma_f32_16x16x16_bf16 %0, %1, %2, %0\n\ts_nop 7"
                 : "+v"(c) : "v"(a), "v"(b));
    return c;
#endif
}

__device__ __forceinline__ unsigned packbf2(float a, float b) {
    __hip_bfloat162 h = __float22bfloat162_rn(float2{a, b});
    union { __hip_bfloat162 h; unsigned u; } v; v.h = h;
    return v.u;
}

__device__ __forceinline__ float fmax3(float a, float b, float c) {
    return fmaxf(fmaxf(a, b), c);   // clang fuses to v_max3_f32
}

// ---------------------------------------------------------------------------
// Shared GEMM body: C[m][n] = sum_k A[m][k] * W[n][k] + bias[n]
// M=8192, N=512, K=512. 128x128 tile, BK=32, 256 threads (4 waves 2x2).
// ---------------------------------------------------------------------------
template<int A_BF16>
__device__ __forceinline__ void gemm_body(const void* Ap, const float* W,
                                          f32x4 (&acc)[4][4],
                                          unsigned short (*As)[40], unsigned short (*Bs)[40],
                                          int bm, int bn, int t)
{
    constexpr int Kdim = 512;
    const int lane = t & 63, g = lane >> 4, c = lane & 15;
    const int w = t >> 6, wr = w >> 1, wc = w & 1;

    uint4  paB[2];
    float4 paF[4];
    float4 pw[4];
    const int ccB = (t & 3) * 8, r0B = t >> 2;
    const int c4  = (t & 7) * 4, r0F = t >> 3;

    if (A_BF16) {
        const unsigned short* A = (const unsigned short*)Ap;
        for (int p = 0; p < 2; ++p)
            paB[p] = *(const uint4*)(A + (size_t)(bm + r0B + p * 64) * Kdim + ccB);
    } else {
        const float* A = (const float*)Ap;
        for (int p = 0; p < 4; ++p)
            paF[p] = *(const float4*)(A + (size_t)(bm + r0F + p * 32) * Kdim + c4);
    }
    for (int p = 0; p < 4; ++p)
        pw[p] = *(const float4*)(W + (size_t)(bn + r0F + p * 32) * Kdim + c4);

    for (int k0 = 0; k0 < Kdim; k0 += 32) {
        __syncthreads();
        if (A_BF16) {
            for (int p = 0; p < 2; ++p)
                *(uint4*)&As[r0B + p * 64][ccB] = paB[p];
        } else {
            for (int p = 0; p < 4; ++p) {
                float4 v = paF[p];
                ushort4 hv;
                hv.x = f2bf(v.x); hv.y = f2bf(v.y); hv.z = f2bf(v.z); hv.w = f2bf(v.w);
                *(ushort4*)&As[r0F + p * 32][c4] = hv;
            }
        }
        for (int p = 0; p < 4; ++p) {
            float4 v = pw[p];
            ushort4 hv;
            hv.x = f2bf(v.x); hv.y = f2bf(v.y); hv.z = f2bf(v.z); hv.w = f2bf(v.w);
            *(ushort4*)&Bs[r0F + p * 32][c4] = hv;
        }
        __syncthreads();
        if (k0 + 32 < Kdim) {
            const int kn = k0 + 32;
            if (A_BF16) {
                const unsigned short* A = (const unsigned short*)Ap;
                for (int p = 0; p < 2; ++p)
                    paB[p] = *(const uint4*)(A + (size_t)(bm + r0B + p * 64) * Kdim + kn + ccB);
            } else {
                const float* A = (const float*)Ap;
                for (int p = 0; p < 4; ++p)
                    paF[p] = *(const float4*)(A + (size_t)(bm + r0F + p * 32) * Kdim + kn + c4);
            }
            for (int p = 0; p < 4; ++p)
                pw[p] = *(const float4*)(W + (size_t)(bn + r0F + p * 32) * Kdim + kn + c4);
        }
        bf16x8 af[4], bfr[4];
        for (int i = 0; i < 4; ++i)
            af[i] = *(const bf16x8*)&As[wr * 64 + i * 16 + c][g * 8];
        for (int j = 0; j < 4; ++j)
            bfr[j] = *(const bf16x8*)&Bs[wc * 64 + j * 16 + c][g * 8];
        for (int i = 0; i < 4; ++i)
            for (int j = 0; j < 4; ++j)
                acc[i][j] = __builtin_amdgcn_mfma_f32_16x16x32_bf16(af[i], bfr[j], acc[i][j], 0, 0, 0);
    }
}

// Fused Q/K/V projections: blockIdx.z selects weight set. q fp32 input.
// Q output is PRE-SCALED by 0.125*log2(e) (folded into QK^T C operand).
__global__ __launch_bounds__(256, 2)
void gemm_qkv(const float* __restrict__ q,
              const float* __restrict__ Wq, const float* __restrict__ bq,
              const float* __restrict__ Wk, const float* __restrict__ bk,
              const float* __restrict__ Wv, const float* __restrict__ bv,
              unsigned short* __restrict__ Qo, unsigned short* __restrict__ Ko,
              unsigned short* __restrict__ Vo)
{
    __shared__ unsigned short As[128][40];
    __shared__ unsigned short Bs[128][40];
    const int t = threadIdx.x, z = blockIdx.z;
    const int lane = t & 63, g = lane >> 4, c = lane & 15;
    const int w = t >> 6, wr = w >> 1, wc = w & 1;
    const int bm = blockIdx.x * 128, bn = blockIdx.y * 128;

    const float* W    = (z == 0) ? Wq : (z == 1) ? Wk : Wv;
    const float* bias = (z == 0) ? bq : (z == 1) ? bk : bv;
    unsigned short* Out = (z == 0) ? Qo : (z == 1) ? Ko : Vo;
    const float osc = (z == 0) ? 0.125f * 1.44269504f : 1.0f;

    f32x4 acc[4][4] = {};
    gemm_body<0>((const void*)q, W, acc, As, Bs, bm, bn, t);

    float bv4[4];
    for (int j = 0; j < 4; ++j) bv4[j] = bias[bn + wc * 64 + j * 16 + c];
    for (int i = 0; i < 4; ++i)
        for (int j = 0; j < 4; ++j)
            for (int r = 0; r < 4; ++r) {
                int m = bm + wr * 64 + i * 16 + 4 * g + r;
                int n = bn + wc * 64 + j * 16 + c;
                float val = (acc[i][j][r] + bv4[j]) * osc;
                int b = m >> 12, s = m & 4095, h = n >> 6, d = n & 63;
                if (z < 2)
                    Out[((((size_t)b * 8 + h) * 4096 + s) << 6) + d] = f2bf(val);
                else
                    Out[(((size_t)b * 8 + h) * 64 + d) * 4096 + s] = f2bf(val);
            }
}

// Output projection: A bf16 [8192][512], out fp32 [8192][512].
__global__ __launch_bounds__(256, 2)
void gemm_out(const unsigned short* __restrict__ A, const float* __restrict__ W,
              const float* __restrict__ bias, float* __restrict__ Out)
{
    __shared__ unsigned short As[128][40];
    __shared__ unsigned short Bs[128][40];
    const int t = threadIdx.x;
    const int lane = t & 63, g = lane >> 4, c = lane & 15;
    const int w = t >> 6, wr = w >> 1, wc = w & 1;
    const int bm = blockIdx.x * 128, bn = blockIdx.y * 128;

    f32x4 acc[4][4] = {};
    gemm_body<1>((const void*)A, W, acc, As, Bs, bm, bn, t);

    float bv4[4];
    for (int j = 0; j < 4; ++j) bv4[j] = bias[bn + wc * 64 + j * 16 + c];
    for (int i = 0; i < 4; ++i)
        for (int j = 0; j < 4; ++j)
            for (int r = 0; r < 4; ++r) {
                int m = bm + wr * 64 + i * 16 + 4 * g + r;
                int n = bn + wc * 64 + j * 16 + c;
                Out[(size_t)m * 512 + n] = acc[i][j][r] + bv4[j];
            }
}

// ---------------------------------------------------------------------------
// Flash attention fwd. Q(pre-scaled),K: [16][4096][64] bf16; VT: [16][64][4096].
// 8 WAVES (512 thr), 128 Q-rows/block, ONE 16-row q-group per wave -> same
// instruction totals as the 4-wave version but 2x resident waves (16/CU,
// ~4/SIMD): VALU of one wave overlaps MFMA of another (m114).
// Double-buffered LDS, one barrier/tile; loads for t+1 issued right after
// the barrier. QK^T C-init = -m. Swizzled conflict-free LDS. XCD swizzle.
// ---------------------------------------------------------------------------
__global__ __launch_bounds__(512, 4)
void attn128(const unsigned short* __restrict__ Q, const unsigned short* __restrict__ Kh,
             const unsigned short* __restrict__ VT, unsigned short* __restrict__ Mo)
{
    __shared__ unsigned short Ks[2 * 64 * 64];   // double-buffered, swizzled
    __shared__ unsigned short Vs[2 * 64 * 64];

    const int t = threadIdx.x, w = t >> 6, lane = t & 63, g = lane >> 4, c = lane & 15;
    // XCD-aware swizzle: 512 blocks, 8 XCDs, bijective (512%8==0).
    const int idp = (blockIdx.x & 7) * 64 + (blockIdx.x >> 3);
    const int bh = idp >> 5;
    const int q0 = (idp & 31) * 128;
    const unsigned short* Qb = Q + (size_t)bh * 4096 * 64;
    const unsigned short* Kb = Kh + (size_t)bh * 4096 * 64;
    const unsigned short* Vb = VT + (size_t)bh * 64 * 4096;

    // one q-group per wave: rows q0 + w*16 + c
    bf16x8 qf0, qf1;
    {
        int qr = q0 + w * 16 + c;
        qf0 = *(const bf16x8*)(Qb + (size_t)qr * 64 + g * 8);
        qf1 = *(const bf16x8*)(Qb + (size_t)qr * 64 + 32 + g * 8);
    }

    f32x4 o[4] = {};          // o[nd][r] = O[q-local 4g+r][d = nd*16+c]
    f32x4 lacc = {};
    float nm = 0.f;           // -m (exp2 domain) for this lane's q-row (c)

    bf16x4 ones;
    ones[0] = ones[1] = ones[2] = ones[3] = (short)0x3F80;   // bf16 1.0

    // staging: 512 threads, 1 swizzled 16B slot per thread per array
    const int srow = t >> 3, s0 = t & 7;
    const int scol = s0 * 8;
    const int woff = srow * 64 + ((s0 ^ (srow & 7)) << 3);
    const unsigned short* kp0 = Kb + (size_t)srow * 64 + scol;
    const unsigned short* vp0 = Vb + (size_t)srow * 4096 + scol;

    uint4 ka = *(const uint4*)(kp0);
    uint4 va = *(const uint4*)(vp0);
    // prologue: stage tile 0 into buffer 0
    *(uint4*)&Ks[woff] = ka;
    *(uint4*)&Vs[woff] = va;

    const float THR = 10.f;                   // p bounded by 2^10
    const int c7 = c & 7;

    auto tile_iter = [&](int jt, const unsigned short* Kc, const unsigned short* Vc,
                         unsigned short* Kn, unsigned short* Vn) {
        __syncthreads();
        // issue next tile's loads right after the barrier: span compute phase
        if (jt < 63) {
            ka = *(const uint4*)(kp0 + (size_t)(jt + 1) * 4096);
            va = *(const uint4*)(vp0 + (jt + 1) * 64);
        }

        // S^T = K Q^T, accumulator C-initialized with -m (Q pre-scaled)
        f32x4 ta[4];
        #pragma unroll
        for (int nt = 0; nt < 4; ++nt) {
            int row = nt * 16 + c;
            bf16x8 kf0 = *(const bf16x8*)&Kc[row * 64 + ((g ^ c7) << 3)];
            bf16x8 kf1 = *(const bf16x8*)&Kc[row * 64 + (((4 + g) ^ c7) << 3)];
            f32x4 z = {nm, nm, nm, nm};
            z = __builtin_amdgcn_mfma_f32_16x16x32_bf16(kf0, qf0, z, 0, 0, 0);
            z = __builtin_amdgcn_mfma_f32_16x16x32_bf16(kf1, qf1, z, 0, 0, 0);
            ta[nt] = z;
        }

        // per-lane max via max3 tree
        float tm = fmax3(fmax3(fmax3(ta[0][0], ta[0][1], ta[0][2]),
                               fmax3(ta[0][3], ta[1][0], ta[1][1]),
                               fmax3(ta[1][2], ta[1][3], ta[2][0])),
                         fmax3(ta[2][1], ta[2][2], ta[2][3]),
                         fmax3(fmax3(ta[3][0], ta[3][1], ta[3][2]), ta[3][3], ta[3][3]));
        if (!__all(tm <= THR)) {
            // rare: reduce max across the 4 g-groups (same q-row c)
            float pm = tm;
            pm = fmaxf(pm, __shfl_xor(pm, 16));
            pm = fmaxf(pm, __shfl_xor(pm, 32));
            float dm = fmaxf(pm, 0.f);
            nm -= dm;
            float al = exp2f(-dm);
            #pragma unroll
            for (int nt = 0; nt < 4; ++nt)
                #pragma unroll
                for (int r = 0; r < 4; ++r) ta[nt][r] -= dm;
            #pragma unroll
            for (int r = 0; r < 4; ++r) {
                float ar = __shfl(al, 4 * g + r);
                #pragma unroll
                for (int nd = 0; nd < 4; ++nd) o[nd][r] *= ar;
                lacc[r] *= ar;
            }
        }

        // p = 2^t -> bf16 A-fragments
        bf16x4 pf[4];
        #pragma unroll
        for (int nt = 0; nt < 4; ++nt) {
            union { unsigned u[2]; bf16x4 v; } pk;
            pk.u[0] = packbf2(exp2f(ta[nt][0]), exp2f(ta[nt][1]));
            pk.u[1] = packbf2(exp2f(ta[nt][2]), exp2f(ta[nt][3]));
            pf[nt] = pk.v;
        }

        // O += P V ; l += P * ones
        #pragma unroll
        for (int nd = 0; nd < 4; ++nd) {
            int row = nd * 16 + c;
            #pragma unroll
            for (int nt = 0; nt < 4; ++nt) {
                int off = row * 64 + (((2 * nt + (g >> 1)) ^ c7) << 3) + ((g & 1) << 2);
                bf16x4 vf = *(const bf16x4*)&Vc[off];
                o[nd] = mfma16(pf[nt], vf, o[nd]);
            }
        }
        #pragma unroll
        for (int nt = 0; nt < 4; ++nt)
            lacc = mfma16(pf[nt], ones, lacc);

        // stage tile jt+1 into the other buffer (latency hidden under compute)
        if (jt < 63) {
            *(uint4*)&Kn[woff] = ka;
            *(uint4*)&Vn[woff] = va;
        }
    };

    for (int jt2 = 0; jt2 < 64; jt2 += 2) {
        tile_iter(jt2,     &Ks[0],    &Vs[0],    &Ks[4096], &Vs[4096]);
        tile_iter(jt2 + 1, &Ks[4096], &Vs[4096], &Ks[0],    &Vs[0]);
    }

    const int b = bh >> 3, h = bh & 7;
    #pragma unroll
    for (int r = 0; r < 4; ++r) {
        float inv = 1.f / lacc[r];
        int m = b * 4096 + q0 + w * 16 + 4 * g + r;
        #pragma unroll
        for (int nd = 0; nd < 4; ++nd) {
            int n = h * 64 + nd * 16 + c;
            Mo[(size_t)m * 512 + n] = f2bf(o[nd][r] * inv);
        }
    }
}

extern "C" void kernel_launch(void* const* d_in, const int* in_sizes, int n_in,
                              void* d_out, int out_size, void* d_ws, size_t ws_size,
                              hipStream_t stream) {
    const float* q  = (const float*)d_in[0];
    const float* Wq = (const float*)d_in[1];
    const float* bq = (const float*)d_in[2];
    const float* Wk = (const float*)d_in[3];
    const float* bk = (const float*)d_in[4];
    const float* Wv = (const float*)d_in[5];
    const float* bv = (const float*)d_in[6];
    const float* Wo = (const float*)d_in[7];
    const float* bo = (const float*)d_in[8];

    unsigned short* Qb = (unsigned short*)d_ws;            // 8 MB
    unsigned short* Kb = Qb + (size_t)16 * 4096 * 64;      // 8 MB
    unsigned short* Vt = Kb + (size_t)16 * 4096 * 64;      // 8 MB (V^T per head)
    unsigned short* Mg = Vt + (size_t)16 * 4096 * 64;      // merged bf16 [8192][512]

    dim3 gb(256);
    dim3 gqkv(64, 4, 3);
    gemm_qkv<<<gqkv, gb, 0, stream>>>(q, Wq, bq, Wk, bk, Wv, bv, Qb, Kb, Vt);

    dim3 ga(512), gba(512);
    attn128<<<ga, gba, 0, stream>>>(Qb, Kb, Vt, Mg);

    dim3 gg(64, 4);
    gemm_out<<<gg, gb, 0, stream>>>(Mg, Wo, bo, (float*)d_out);
}

// Round 11
// 174.364 us; speedup vs baseline: 1.9862x; 1.0434x over previous
//
#include <hip/hip_runtime.h>
#include <hip/hip_bf16.h>
#include <math.h>

typedef __attribute__((ext_vector_type(8))) short bf16x8;
typedef __attribute__((ext_vector_type(4))) short bf16x4;
typedef __attribute__((ext_vector_type(4))) float f32x4;

__device__ __forceinline__ unsigned short f2bf(float f) {
    union { float f; unsigned int u; } v; v.f = f;
    unsigned int u = v.u;
    u += 0x7fffu + ((u >> 16) & 1u);   // round-to-nearest-even
    return (unsigned short)(u >> 16);
}

__device__ __forceinline__ f32x4 mfma16(bf16x4 a, bf16x4 b, f32x4 c) {
#if __has_builtin(__builtin_amdgcn_mfma_f32_16x16x16bf16_1k)
    return __builtin_amdgcn_mfma_f32_16x16x16bf16_1k(a, b, c, 0, 0, 0);
#else
    asm volatile("v_mfma_f32_16x16x16_bf16 %0, %1, %2, %0\n\ts_nop 7"
                 : "+v"(c) : "v"(a), "v"(b));
    return c;
#endif
}

__device__ __forceinline__ unsigned packbf2(float a, float b) {
    __hip_bfloat162 h = __float22bfloat162_rn(float2{a, b});
    union { __hip_bfloat162 h; unsigned u; } v; v.h = h;
    return v.u;
}

__device__ __forceinline__ float fmax3(float a, float b, float c) {
    return fmaxf(fmaxf(a, b), c);   // clang fuses to v_max3_f32
}

// ---------------------------------------------------------------------------
// Shared GEMM body: C[m][n] = sum_k A[m][k] * W[n][k] + bias[n]
// M=8192, N=512, K=512. 128x128 tile, BK=32, 256 threads (4 waves 2x2).
// ---------------------------------------------------------------------------
template<int A_BF16>
__device__ __forceinline__ void gemm_body(const void* Ap, const float* W,
                                          f32x4 (&acc)[4][4],
                                          unsigned short (*As)[40], unsigned short (*Bs)[40],
                                          int bm, int bn, int t)
{
    constexpr int Kdim = 512;
    const int lane = t & 63, g = lane >> 4, c = lane & 15;
    const int w = t >> 6, wr = w >> 1, wc = w & 1;

    uint4  paB[2];
    float4 paF[4];
    float4 pw[4];
    const int ccB = (t & 3) * 8, r0B = t >> 2;
    const int c4  = (t & 7) * 4, r0F = t >> 3;

    if (A_BF16) {
        const unsigned short* A = (const unsigned short*)Ap;
        for (int p = 0; p < 2; ++p)
            paB[p] = *(const uint4*)(A + (size_t)(bm + r0B + p * 64) * Kdim + ccB);
    } else {
        const float* A = (const float*)Ap;
        for (int p = 0; p < 4; ++p)
            paF[p] = *(const float4*)(A + (size_t)(bm + r0F + p * 32) * Kdim + c4);
    }
    for (int p = 0; p < 4; ++p)
        pw[p] = *(const float4*)(W + (size_t)(bn + r0F + p * 32) * Kdim + c4);

    for (int k0 = 0; k0 < Kdim; k0 += 32) {
        __syncthreads();
        if (A_BF16) {
            for (int p = 0; p < 2; ++p)
                *(uint4*)&As[r0B + p * 64][ccB] = paB[p];
        } else {
            for (int p = 0; p < 4; ++p) {
                float4 v = paF[p];
                ushort4 hv;
                hv.x = f2bf(v.x); hv.y = f2bf(v.y); hv.z = f2bf(v.z); hv.w = f2bf(v.w);
                *(ushort4*)&As[r0F + p * 32][c4] = hv;
            }
        }
        for (int p = 0; p < 4; ++p) {
            float4 v = pw[p];
            ushort4 hv;
            hv.x = f2bf(v.x); hv.y = f2bf(v.y); hv.z = f2bf(v.z); hv.w = f2bf(v.w);
            *(ushort4*)&Bs[r0F + p * 32][c4] = hv;
        }
        __syncthreads();
        if (k0 + 32 < Kdim) {
            const int kn = k0 + 32;
            if (A_BF16) {
                const unsigned short* A = (const unsigned short*)Ap;
                for (int p = 0; p < 2; ++p)
                    paB[p] = *(const uint4*)(A + (size_t)(bm + r0B + p * 64) * Kdim + kn + ccB);
            } else {
                const float* A = (const float*)Ap;
                for (int p = 0; p < 4; ++p)
                    paF[p] = *(const float4*)(A + (size_t)(bm + r0F + p * 32) * Kdim + kn + c4);
            }
            for (int p = 0; p < 4; ++p)
                pw[p] = *(const float4*)(W + (size_t)(bn + r0F + p * 32) * Kdim + kn + c4);
        }
        bf16x8 af[4], bfr[4];
        for (int i = 0; i < 4; ++i)
            af[i] = *(const bf16x8*)&As[wr * 64 + i * 16 + c][g * 8];
        for (int j = 0; j < 4; ++j)
            bfr[j] = *(const bf16x8*)&Bs[wc * 64 + j * 16 + c][g * 8];
        for (int i = 0; i < 4; ++i)
            for (int j = 0; j < 4; ++j)
                acc[i][j] = __builtin_amdgcn_mfma_f32_16x16x32_bf16(af[i], bfr[j], acc[i][j], 0, 0, 0);
    }
}

// Fused Q/K/V projections: blockIdx.z selects weight set. q fp32 input.
// Q output is PRE-SCALED by 0.125*log2(e) (folded into QK^T C operand).
__global__ __launch_bounds__(256, 2)
void gemm_qkv(const float* __restrict__ q,
              const float* __restrict__ Wq, const float* __restrict__ bq,
              const float* __restrict__ Wk, const float* __restrict__ bk,
              const float* __restrict__ Wv, const float* __restrict__ bv,
              unsigned short* __restrict__ Qo, unsigned short* __restrict__ Ko,
              unsigned short* __restrict__ Vo)
{
    __shared__ unsigned short As[128][40];
    __shared__ unsigned short Bs[128][40];
    const int t = threadIdx.x, z = blockIdx.z;
    const int lane = t & 63, g = lane >> 4, c = lane & 15;
    const int w = t >> 6, wr = w >> 1, wc = w & 1;
    const int bm = blockIdx.x * 128, bn = blockIdx.y * 128;

    const float* W    = (z == 0) ? Wq : (z == 1) ? Wk : Wv;
    const float* bias = (z == 0) ? bq : (z == 1) ? bk : bv;
    unsigned short* Out = (z == 0) ? Qo : (z == 1) ? Ko : Vo;
    const float osc = (z == 0) ? 0.125f * 1.44269504f : 1.0f;

    f32x4 acc[4][4] = {};
    gemm_body<0>((const void*)q, W, acc, As, Bs, bm, bn, t);

    float bv4[4];
    for (int j = 0; j < 4; ++j) bv4[j] = bias[bn + wc * 64 + j * 16 + c];
    for (int i = 0; i < 4; ++i)
        for (int j = 0; j < 4; ++j)
            for (int r = 0; r < 4; ++r) {
                int m = bm + wr * 64 + i * 16 + 4 * g + r;
                int n = bn + wc * 64 + j * 16 + c;
                float val = (acc[i][j][r] + bv4[j]) * osc;
                int b = m >> 12, s = m & 4095, h = n >> 6, d = n & 63;
                if (z < 2)
                    Out[((((size_t)b * 8 + h) * 4096 + s) << 6) + d] = f2bf(val);
                else
                    Out[(((size_t)b * 8 + h) * 64 + d) * 4096 + s] = f2bf(val);
            }
}

// Output projection: A bf16 [8192][512], out fp32 [8192][512].
__global__ __launch_bounds__(256, 2)
void gemm_out(const unsigned short* __restrict__ A, const float* __restrict__ W,
              const float* __restrict__ bias, float* __restrict__ Out)
{
    __shared__ unsigned short As[128][40];
    __shared__ unsigned short Bs[128][40];
    const int t = threadIdx.x;
    const int lane = t & 63, g = lane >> 4, c = lane & 15;
    const int w = t >> 6, wr = w >> 1, wc = w & 1;
    const int bm = blockIdx.x * 128, bn = blockIdx.y * 128;

    f32x4 acc[4][4] = {};
    gemm_body<1>((const void*)A, W, acc, As, Bs, bm, bn, t);

    float bv4[4];
    for (int j = 0; j < 4; ++j) bv4[j] = bias[bn + wc * 64 + j * 16 + c];
    for (int i = 0; i < 4; ++i)
        for (int j = 0; j < 4; ++j)
            for (int r = 0; r < 4; ++r) {
                int m = bm + wr * 64 + i * 16 + 4 * g + r;
                int n = bn + wc * 64 + j * 16 + c;
                Out[(size_t)m * 512 + n] = acc[i][j][r] + bv4[j];
            }
}

// ---------------------------------------------------------------------------
// Flash attention fwd. Q(pre-scaled),K: [16][4096][64] bf16; VT: [16][64][4096].
// 8 waves (512 thr), 128 Q-rows/block, one 16-row q-group per wave.
// KV-tile 128 = two 64-key halves, ONE barrier per 128 keys: double-length
// no-sync window lets the 4 waves/SIMD de-phase so softmax-VALU of one wave
// overlaps MFMA of another (m114). T5 setprio around MFMA clusters.
// LDS: K [128][64] + V^T [64][128] per buffer, double-buffered (64 KB),
// stride == 0 mod 32 banks, 16B-slot XOR swizzle slot^=(row&7) both sides.
// All prefetch state in NAMED registers (no runtime-indexed arrays).
// ---------------------------------------------------------------------------
__global__ __launch_bounds__(512, 4)
void attn128(const unsigned short* __restrict__ Q, const unsigned short* __restrict__ Kh,
             const unsigned short* __restrict__ VT, unsigned short* __restrict__ Mo)
{
    __shared__ unsigned short Ks[2 * 128 * 64];   // [buf][row 0..127][64], swizzled
    __shared__ unsigned short Vs[2 * 64 * 128];   // [buf][d 0..63][128 keys], swizzled

    const int t = threadIdx.x, w = t >> 6, lane = t & 63, g = lane >> 4, c = lane & 15;
    // XCD-aware swizzle: 512 blocks, 8 XCDs, bijective (512%8==0).
    const int idp = (blockIdx.x & 7) * 64 + (blockIdx.x >> 3);
    const int bh = idp >> 5;
    const int q0 = (idp & 31) * 128;
    const unsigned short* Qb = Q + (size_t)bh * 4096 * 64;
    const unsigned short* Kb = Kh + (size_t)bh * 4096 * 64;
    const unsigned short* Vb = VT + (size_t)bh * 64 * 4096;

    // one q-group per wave: rows q0 + w*16 + c
    bf16x8 qf0, qf1;
    {
        int qr = q0 + w * 16 + c;
        qf0 = *(const bf16x8*)(Qb + (size_t)qr * 64 + g * 8);
        qf1 = *(const bf16x8*)(Qb + (size_t)qr * 64 + 32 + g * 8);
    }

    f32x4 o[4] = {};          // o[nd][r] = O[q-local 4g+r][d = nd*16+c]
    f32x4 lacc = {};
    float nm = 0.f;           // -m (exp2 domain) for this lane's q-row (c)

    bf16x4 ones;
    ones[0] = ones[1] = ones[2] = ones[3] = (short)0x3F80;   // bf16 1.0

    // staging: 512 threads, each covers one 16B slot of each 64x64 half
    const int srow = t >> 3, s0 = t & 7;
    const int scol = s0 * 8, r7 = srow & 7;
    const int woffK  = srow * 64 + ((s0 ^ r7) << 3);            // K rows 0-63
    const int woffKB = (64 + srow) * 64 + ((s0 ^ r7) << 3);     // K rows 64-127
    const int woffV  = srow * 128 + ((s0 ^ r7) << 3);           // V slots 0-7
    const int woffVB = srow * 128 + ((8 + (s0 ^ r7)) << 3);     // V slots 8-15
    const unsigned short* kpA = Kb + (size_t)srow * 64 + scol;          // tile stride 8192
    const unsigned short* vpA = Vb + (size_t)srow * 4096 + scol;        // tile stride 128

    uint4 kaA = *(const uint4*)(kpA);
    uint4 kaB = *(const uint4*)(kpA + 64 * 64);
    uint4 vaA = *(const uint4*)(vpA);
    uint4 vaB = *(const uint4*)(vpA + 64);
    // prologue: stage tile 0 into buffer 0
    *(uint4*)&Ks[woffK]  = kaA;
    *(uint4*)&Ks[woffKB] = kaB;
    *(uint4*)&Vs[woffV]  = vaA;
    *(uint4*)&Vs[woffVB] = vaB;

    const float THR = 10.f;                   // p bounded by 2^10
    const int c7 = c & 7;

    // compute one 64-key half: Kc = K half base (64 rows x 64), Vc = V buffer
    // base ([64][128]), h8 = V slot base (0 or 8)
    auto half_iter = [&](const unsigned short* Kc, const unsigned short* Vc, int h8) {
        // S^T = K Q^T, accumulator C-initialized with -m (Q pre-scaled)
        f32x4 ta[4];
        __builtin_amdgcn_s_setprio(1);
        #pragma unroll
        for (int nt = 0; nt < 4; ++nt) {
            int row = nt * 16 + c;
            bf16x8 kf0 = *(const bf16x8*)&Kc[row * 64 + ((g ^ c7) << 3)];
            bf16x8 kf1 = *(const bf16x8*)&Kc[row * 64 + (((4 + g) ^ c7) << 3)];
            f32x4 z = {nm, nm, nm, nm};
            z = __builtin_amdgcn_mfma_f32_16x16x32_bf16(kf0, qf0, z, 0, 0, 0);
            z = __builtin_amdgcn_mfma_f32_16x16x32_bf16(kf1, qf1, z, 0, 0, 0);
            ta[nt] = z;
        }
        __builtin_amdgcn_s_setprio(0);

        // per-lane max via max3 tree
        float tm = fmax3(fmax3(fmax3(ta[0][0], ta[0][1], ta[0][2]),
                               fmax3(ta[0][3], ta[1][0], ta[1][1]),
                               fmax3(ta[1][2], ta[1][3], ta[2][0])),
                         fmax3(ta[2][1], ta[2][2], ta[2][3]),
                         fmax3(fmax3(ta[3][0], ta[3][1], ta[3][2]), ta[3][3], ta[3][3]));
        if (!__all(tm <= THR)) {
            // rare: reduce max across the 4 g-groups (same q-row c)
            float pm = tm;
            pm = fmaxf(pm, __shfl_xor(pm, 16));
            pm = fmaxf(pm, __shfl_xor(pm, 32));
            float dm = fmaxf(pm, 0.f);
            nm -= dm;
            float al = exp2f(-dm);
            #pragma unroll
            for (int nt = 0; nt < 4; ++nt)
                #pragma unroll
                for (int r = 0; r < 4; ++r) ta[nt][r] -= dm;
            #pragma unroll
            for (int r = 0; r < 4; ++r) {
                float ar = __shfl(al, 4 * g + r);
                #pragma unroll
                for (int nd = 0; nd < 4; ++nd) o[nd][r] *= ar;
                lacc[r] *= ar;
            }
        }

        // p = 2^t -> bf16 A-fragments
        bf16x4 pf[4];
        #pragma unroll
        for (int nt = 0; nt < 4; ++nt) {
            union { unsigned u[2]; bf16x4 v; } pk;
            pk.u[0] = packbf2(exp2f(ta[nt][0]), exp2f(ta[nt][1]));
            pk.u[1] = packbf2(exp2f(ta[nt][2]), exp2f(ta[nt][3]));
            pf[nt] = pk.v;
        }

        // O += P V ; l += P * ones
        __builtin_amdgcn_s_setprio(1);
        #pragma unroll
        for (int nd = 0; nd < 4; ++nd) {
            int row = nd * 16 + c;
            #pragma unroll
            for (int nt = 0; nt < 4; ++nt) {
                int off = row * 128 + ((h8 + ((2 * nt + (g >> 1)) ^ c7)) << 3) + ((g & 1) << 2);
                bf16x4 vf = *(const bf16x4*)&Vc[off];
                o[nd] = mfma16(pf[nt], vf, o[nd]);
            }
        }
        #pragma unroll
        for (int nt = 0; nt < 4; ++nt)
            lacc = mfma16(pf[nt], ones, lacc);
        __builtin_amdgcn_s_setprio(0);
    };

    // one iteration = 128 keys, ONE barrier
    auto tile_iter = [&](int it, const unsigned short* Kc, const unsigned short* Vc,
                         unsigned short* Kn, unsigned short* Vn) {
        __syncthreads();
        // issue next 128-key tile's loads right after the barrier
        if (it < 31) {
            const unsigned short* kp = kpA + (size_t)(it + 1) * 8192;
            const unsigned short* vp = vpA + (it + 1) * 128;
            kaA = *(const uint4*)(kp);
            kaB = *(const uint4*)(kp + 64 * 64);
            vaA = *(const uint4*)(vp);
            vaB = *(const uint4*)(vp + 64);
        }
        half_iter(Kc, Vc, 0);
        half_iter(Kc + 64 * 64, Vc, 8);
        // stage next tile into the other buffer (latency hidden under compute)
        if (it < 31) {
            *(uint4*)&Kn[woffK]  = kaA;
            *(uint4*)&Kn[woffKB] = kaB;
            *(uint4*)&Vn[woffV]  = vaA;
            *(uint4*)&Vn[woffVB] = vaB;
        }
    };

    for (int it2 = 0; it2 < 32; it2 += 2) {
        tile_iter(it2,     &Ks[0],    &Vs[0],    &Ks[8192], &Vs[8192]);
        tile_iter(it2 + 1, &Ks[8192], &Vs[8192], &Ks[0],    &Vs[0]);
    }

    const int b = bh >> 3, h = bh & 7;
    #pragma unroll
    for (int r = 0; r < 4; ++r) {
        float inv = 1.f / lacc[r];
        int m = b * 4096 + q0 + w * 16 + 4 * g + r;
        #pragma unroll
        for (int nd = 0; nd < 4; ++nd) {
            int n = h * 64 + nd * 16 + c;
            Mo[(size_t)m * 512 + n] = f2bf(o[nd][r] * inv);
        }
    }
}

extern "C" void kernel_launch(void* const* d_in, const int* in_sizes, int n_in,
                              void* d_out, int out_size, void* d_ws, size_t ws_size,
                              hipStream_t stream) {
    const float* q  = (const float*)d_in[0];
    const float* Wq = (const float*)d_in[1];
    const float* bq = (const float*)d_in[2];
    const float* Wk = (const float*)d_in[3];
    const float* bk = (const float*)d_in[4];
    const float* Wv = (const float*)d_in[5];
    const float* bv = (const float*)d_in[6];
    const float* Wo = (const float*)d_in[7];
    const float* bo = (const float*)d_in[8];

    unsigned short* Qb = (unsigned short*)d_ws;            // 8 MB
    unsigned short* Kb = Qb + (size_t)16 * 4096 * 64;      // 8 MB
    unsigned short* Vt = Kb + (size_t)16 * 4096 * 64;      // 8 MB (V^T per head)
    unsigned short* Mg = Vt + (size_t)16 * 4096 * 64;      // merged bf16 [8192][512]

    dim3 gb(256);
    dim3 gqkv(64, 4, 3);
    gemm_qkv<<<gqkv, gb, 0, stream>>>(q, Wq, bq, Wk, bk, Wv, bv, Qb, Kb, Vt);

    dim3 ga(512), gba(512);
    attn128<<<ga, gba, 0, stream>>>(Qb, Kb, Vt, Mg);

    dim3 gg(64, 4);
    gemm_out<<<gg, gb, 0, stream>>>(Mg, Wo, bo, (float*)d_out);
}

// Round 12
// 173.671 us; speedup vs baseline: 1.9941x; 1.0040x over previous
//
#include <hip/hip_runtime.h>
#include <hip/hip_bf16.h>
#include <math.h>

typedef __attribute__((ext_vector_type(8))) short bf16x8;
typedef __attribute__((ext_vector_type(4))) short bf16x4;
typedef __attribute__((ext_vector_type(4))) float f32x4;

__device__ __forceinline__ unsigned short f2bf(float f) {
    union { float f; unsigned int u; } v; v.f = f;
    unsigned int u = v.u;
    u += 0x7fffu + ((u >> 16) & 1u);   // round-to-nearest-even
    return (unsigned short)(u >> 16);
}

__device__ __forceinline__ f32x4 mfma16(bf16x4 a, bf16x4 b, f32x4 c) {
#if __has_builtin(__builtin_amdgcn_mfma_f32_16x16x16bf16_1k)
    return __builtin_amdgcn_mfma_f32_16x16x16bf16_1k(a, b, c, 0, 0, 0);
#else
    asm volatile("v_mfma_f32_16x16x16_bf16 %0, %1, %2, %0\n\ts_nop 7"
                 : "+v"(c) : "v"(a), "v"(b));
    return c;
#endif
}

__device__ __forceinline__ unsigned packbf2(float a, float b) {
    __hip_bfloat162 h = __float22bfloat162_rn(float2{a, b});
    union { __hip_bfloat162 h; unsigned u; } v; v.h = h;
    return v.u;
}

__device__ __forceinline__ float fmax3(float a, float b, float c) {
    return fmaxf(fmaxf(a, b), c);   // clang fuses to v_max3_f32
}

// ---------------------------------------------------------------------------
// Shared GEMM body: C[m][n] = sum_k A[m][k] * W[n][k] + bias[n]
// M=8192, N=512, K=512. 128x128 tile, BK=32, 256 threads (4 waves 2x2).
// ---------------------------------------------------------------------------
template<int A_BF16>
__device__ __forceinline__ void gemm_body(const void* Ap, const float* W,
                                          f32x4 (&acc)[4][4],
                                          unsigned short (*As)[40], unsigned short (*Bs)[40],
                                          int bm, int bn, int t)
{
    constexpr int Kdim = 512;
    const int lane = t & 63, g = lane >> 4, c = lane & 15;
    const int w = t >> 6, wr = w >> 1, wc = w & 1;

    uint4  paB[2];
    float4 paF[4];
    float4 pw[4];
    const int ccB = (t & 3) * 8, r0B = t >> 2;
    const int c4  = (t & 7) * 4, r0F = t >> 3;

    if (A_BF16) {
        const unsigned short* A = (const unsigned short*)Ap;
        for (int p = 0; p < 2; ++p)
            paB[p] = *(const uint4*)(A + (size_t)(bm + r0B + p * 64) * Kdim + ccB);
    } else {
        const float* A = (const float*)Ap;
        for (int p = 0; p < 4; ++p)
            paF[p] = *(const float4*)(A + (size_t)(bm + r0F + p * 32) * Kdim + c4);
    }
    for (int p = 0; p < 4; ++p)
        pw[p] = *(const float4*)(W + (size_t)(bn + r0F + p * 32) * Kdim + c4);

    for (int k0 = 0; k0 < Kdim; k0 += 32) {
        __syncthreads();
        if (A_BF16) {
            for (int p = 0; p < 2; ++p)
                *(uint4*)&As[r0B + p * 64][ccB] = paB[p];
        } else {
            for (int p = 0; p < 4; ++p) {
                float4 v = paF[p];
                ushort4 hv;
                hv.x = f2bf(v.x); hv.y = f2bf(v.y); hv.z = f2bf(v.z); hv.w = f2bf(v.w);
                *(ushort4*)&As[r0F + p * 32][c4] = hv;
            }
        }
        for (int p = 0; p < 4; ++p) {
            float4 v = pw[p];
            ushort4 hv;
            hv.x = f2bf(v.x); hv.y = f2bf(v.y); hv.z = f2bf(v.z); hv.w = f2bf(v.w);
            *(ushort4*)&Bs[r0F + p * 32][c4] = hv;
        }
        __syncthreads();
        if (k0 + 32 < Kdim) {
            const int kn = k0 + 32;
            if (A_BF16) {
                const unsigned short* A = (const unsigned short*)Ap;
                for (int p = 0; p < 2; ++p)
                    paB[p] = *(const uint4*)(A + (size_t)(bm + r0B + p * 64) * Kdim + kn + ccB);
            } else {
                const float* A = (const float*)Ap;
                for (int p = 0; p < 4; ++p)
                    paF[p] = *(const float4*)(A + (size_t)(bm + r0F + p * 32) * Kdim + kn + c4);
            }
            for (int p = 0; p < 4; ++p)
                pw[p] = *(const float4*)(W + (size_t)(bn + r0F + p * 32) * Kdim + kn + c4);
        }
        bf16x8 af[4], bfr[4];
        for (int i = 0; i < 4; ++i)
            af[i] = *(const bf16x8*)&As[wr * 64 + i * 16 + c][g * 8];
        for (int j = 0; j < 4; ++j)
            bfr[j] = *(const bf16x8*)&Bs[wc * 64 + j * 16 + c][g * 8];
        for (int i = 0; i < 4; ++i)
            for (int j = 0; j < 4; ++j)
                acc[i][j] = __builtin_amdgcn_mfma_f32_16x16x32_bf16(af[i], bfr[j], acc[i][j], 0, 0, 0);
    }
}

// Fused Q/K/V projections: blockIdx.z selects weight set. q fp32 input.
// Q output is PRE-SCALED by 0.125*log2(e) (folded into QK^T C operand).
__global__ __launch_bounds__(256, 2)
void gemm_qkv(const float* __restrict__ q,
              const float* __restrict__ Wq, const float* __restrict__ bq,
              const float* __restrict__ Wk, const float* __restrict__ bk,
              const float* __restrict__ Wv, const float* __restrict__ bv,
              unsigned short* __restrict__ Qo, unsigned short* __restrict__ Ko,
              unsigned short* __restrict__ Vo)
{
    __shared__ unsigned short As[128][40];
    __shared__ unsigned short Bs[128][40];
    const int t = threadIdx.x, z = blockIdx.z;
    const int lane = t & 63, g = lane >> 4, c = lane & 15;
    const int w = t >> 6, wr = w >> 1, wc = w & 1;
    const int bm = blockIdx.x * 128, bn = blockIdx.y * 128;

    const float* W    = (z == 0) ? Wq : (z == 1) ? Wk : Wv;
    const float* bias = (z == 0) ? bq : (z == 1) ? bk : bv;
    unsigned short* Out = (z == 0) ? Qo : (z == 1) ? Ko : Vo;
    const float osc = (z == 0) ? 0.125f * 1.44269504f : 1.0f;

    f32x4 acc[4][4] = {};
    gemm_body<0>((const void*)q, W, acc, As, Bs, bm, bn, t);

    float bv4[4];
    for (int j = 0; j < 4; ++j) bv4[j] = bias[bn + wc * 64 + j * 16 + c];
    for (int i = 0; i < 4; ++i)
        for (int j = 0; j < 4; ++j)
            for (int r = 0; r < 4; ++r) {
                int m = bm + wr * 64 + i * 16 + 4 * g + r;
                int n = bn + wc * 64 + j * 16 + c;
                float val = (acc[i][j][r] + bv4[j]) * osc;
                int b = m >> 12, s = m & 4095, h = n >> 6, d = n & 63;
                if (z < 2)
                    Out[((((size_t)b * 8 + h) * 4096 + s) << 6) + d] = f2bf(val);
                else
                    Out[(((size_t)b * 8 + h) * 64 + d) * 4096 + s] = f2bf(val);
            }
}

// Output projection: A bf16 [8192][512], out fp32 [8192][512].
__global__ __launch_bounds__(256, 2)
void gemm_out(const unsigned short* __restrict__ A, const float* __restrict__ W,
              const float* __restrict__ bias, float* __restrict__ Out)
{
    __shared__ unsigned short As[128][40];
    __shared__ unsigned short Bs[128][40];
    const int t = threadIdx.x;
    const int lane = t & 63, g = lane >> 4, c = lane & 15;
    const int w = t >> 6, wr = w >> 1, wc = w & 1;
    const int bm = blockIdx.x * 128, bn = blockIdx.y * 128;

    f32x4 acc[4][4] = {};
    gemm_body<1>((const void*)A, W, acc, As, Bs, bm, bn, t);

    float bv4[4];
    for (int j = 0; j < 4; ++j) bv4[j] = bias[bn + wc * 64 + j * 16 + c];
    for (int i = 0; i < 4; ++i)
        for (int j = 0; j < 4; ++j)
            for (int r = 0; r < 4; ++r) {
                int m = bm + wr * 64 + i * 16 + 4 * g + r;
                int n = bn + wc * 64 + j * 16 + c;
                Out[(size_t)m * 512 + n] = acc[i][j][r] + bv4[j];
            }
}

// ---------------------------------------------------------------------------
// Flash attention fwd. Q(pre-scaled),K: [16][4096][64] bf16; VT: [16][64][4096].
// 8 waves (512 thr), 128 Q-rows/block, one 16-row q-group per wave.
// KV-tile 128 = two 64-key halves, ONE barrier per 128 keys.
// ANTI-PHASE: odd waves process the halves in reverse order, so at any time
// ~half the waves feed the matrix pipe while the rest feed the trans pipe.
// INTERLEAVE: exp2/pack of score-block nt issues back-to-back with PV MFMAs
// of block nt-1 (independent) -> single-wave trans+matrix co-issue.
// LDS: K [128][64] + V^T [64][128] per buffer, double-buffered (64 KB),
// stride == 0 mod 32 banks, 16B-slot XOR swizzle slot^=(row&7) both sides.
// ---------------------------------------------------------------------------
__global__ __launch_bounds__(512, 4)
void attn128(const unsigned short* __restrict__ Q, const unsigned short* __restrict__ Kh,
             const unsigned short* __restrict__ VT, unsigned short* __restrict__ Mo)
{
    __shared__ unsigned short Ks[2 * 128 * 64];   // [buf][row 0..127][64], swizzled
    __shared__ unsigned short Vs[2 * 64 * 128];   // [buf][d 0..63][128 keys], swizzled

    const int t = threadIdx.x, w = t >> 6, lane = t & 63, g = lane >> 4, c = lane & 15;
    // XCD-aware swizzle: 512 blocks, 8 XCDs, bijective (512%8==0).
    const int idp = (blockIdx.x & 7) * 64 + (blockIdx.x >> 3);
    const int bh = idp >> 5;
    const int q0 = (idp & 31) * 128;
    const unsigned short* Qb = Q + (size_t)bh * 4096 * 64;
    const unsigned short* Kb = Kh + (size_t)bh * 4096 * 64;
    const unsigned short* Vb = VT + (size_t)bh * 64 * 4096;

    // one q-group per wave: rows q0 + w*16 + c
    bf16x8 qf0, qf1;
    {
        int qr = q0 + w * 16 + c;
        qf0 = *(const bf16x8*)(Qb + (size_t)qr * 64 + g * 8);
        qf1 = *(const bf16x8*)(Qb + (size_t)qr * 64 + 32 + g * 8);
    }

    f32x4 o[4] = {};          // o[nd][r] = O[q-local 4g+r][d = nd*16+c]
    f32x4 lacc = {};
    float nm = 0.f;           // -m (exp2 domain) for this lane's q-row (c)

    bf16x4 ones;
    ones[0] = ones[1] = ones[2] = ones[3] = (short)0x3F80;   // bf16 1.0

    // staging: 512 threads, each covers one 16B slot of each 64x64 half
    const int srow = t >> 3, s0 = t & 7;
    const int scol = s0 * 8, r7 = srow & 7;
    const int woffK  = srow * 64 + ((s0 ^ r7) << 3);            // K rows 0-63
    const int woffKB = (64 + srow) * 64 + ((s0 ^ r7) << 3);     // K rows 64-127
    const int woffV  = srow * 128 + ((s0 ^ r7) << 3);           // V slots 0-7
    const int woffVB = srow * 128 + ((8 + (s0 ^ r7)) << 3);     // V slots 8-15
    const unsigned short* kpA = Kb + (size_t)srow * 64 + scol;          // tile stride 8192
    const unsigned short* vpA = Vb + (size_t)srow * 4096 + scol;        // tile stride 128

    uint4 kaA = *(const uint4*)(kpA);
    uint4 kaB = *(const uint4*)(kpA + 64 * 64);
    uint4 vaA = *(const uint4*)(vpA);
    uint4 vaB = *(const uint4*)(vpA + 64);
    // prologue: stage tile 0 into buffer 0
    *(uint4*)&Ks[woffK]  = kaA;
    *(uint4*)&Ks[woffKB] = kaB;
    *(uint4*)&Vs[woffV]  = vaA;
    *(uint4*)&Vs[woffVB] = vaB;

    const float THR = 10.f;                   // p bounded by 2^10
    const int c7 = c & 7;

    // compute one 64-key half: Kc = K half base (64 rows x 64), Vc = V buffer
    // base ([64][128]), h8 = V slot base (0 or 8)
    auto half_iter = [&](const unsigned short* Kc, const unsigned short* Vc, int h8) {
        // S^T = K Q^T, accumulator C-initialized with -m (Q pre-scaled)
        f32x4 ta[4];
        __builtin_amdgcn_s_setprio(1);
        #pragma unroll
        for (int nt = 0; nt < 4; ++nt) {
            int row = nt * 16 + c;
            bf16x8 kf0 = *(const bf16x8*)&Kc[row * 64 + ((g ^ c7) << 3)];
            bf16x8 kf1 = *(const bf16x8*)&Kc[row * 64 + (((4 + g) ^ c7) << 3)];
            f32x4 z = {nm, nm, nm, nm};
            z = __builtin_amdgcn_mfma_f32_16x16x32_bf16(kf0, qf0, z, 0, 0, 0);
            z = __builtin_amdgcn_mfma_f32_16x16x32_bf16(kf1, qf1, z, 0, 0, 0);
            ta[nt] = z;
        }
        __builtin_amdgcn_s_setprio(0);

        // per-lane max via max3 tree
        float tm = fmax3(fmax3(fmax3(ta[0][0], ta[0][1], ta[0][2]),
                               fmax3(ta[0][3], ta[1][0], ta[1][1]),
                               fmax3(ta[1][2], ta[1][3], ta[2][0])),
                         fmax3(ta[2][1], ta[2][2], ta[2][3]),
                         fmax3(fmax3(ta[3][0], ta[3][1], ta[3][2]), ta[3][3], ta[3][3]));
        if (!__all(tm <= THR)) {
            // rare: reduce max across the 4 g-groups (same q-row c)
            float pm = tm;
            pm = fmaxf(pm, __shfl_xor(pm, 16));
            pm = fmaxf(pm, __shfl_xor(pm, 32));
            float dm = fmaxf(pm, 0.f);
            nm -= dm;
            float al = exp2f(-dm);
            #pragma unroll
            for (int nt = 0; nt < 4; ++nt)
                #pragma unroll
                for (int r = 0; r < 4; ++r) ta[nt][r] -= dm;
            #pragma unroll
            for (int r = 0; r < 4; ++r) {
                float ar = __shfl(al, 4 * g + r);
                #pragma unroll
                for (int nd = 0; nd < 4; ++nd) o[nd][r] *= ar;
                lacc[r] *= ar;
            }
        }

        // INTERLEAVED exp2 -> pack -> PV: block nt's MFMAs are independent of
        // block nt+1's exp2s, so trans and matrix pipes co-issue.
        __builtin_amdgcn_s_setprio(1);
        #pragma unroll
        for (int nt = 0; nt < 4; ++nt) {
            union { unsigned u[2]; bf16x4 v; } pk;
            pk.u[0] = packbf2(exp2f(ta[nt][0]), exp2f(ta[nt][1]));
            pk.u[1] = packbf2(exp2f(ta[nt][2]), exp2f(ta[nt][3]));
            bf16x4 pfn = pk.v;
            #pragma unroll
            for (int nd = 0; nd < 4; ++nd) {
                int row = nd * 16 + c;
                int off = row * 128 + ((h8 + ((2 * nt + (g >> 1)) ^ c7)) << 3) + ((g & 1) << 2);
                bf16x4 vf = *(const bf16x4*)&Vc[off];
                o[nd] = mfma16(pfn, vf, o[nd]);
            }
            lacc = mfma16(pfn, ones, lacc);
        }
        __builtin_amdgcn_s_setprio(0);
    };

    // one iteration = 128 keys, ONE barrier. Odd waves take halves in
    // reverse order -> anti-phase pipe usage across waves.
    auto tile_iter = [&](int it, const unsigned short* Kc, const unsigned short* Vc,
                         unsigned short* Kn, unsigned short* Vn) {
        __syncthreads();
        // issue next 128-key tile's loads right after the barrier
        if (it < 31) {
            const unsigned short* kp = kpA + (size_t)(it + 1) * 8192;
            const unsigned short* vp = vpA + (it + 1) * 128;
            kaA = *(const uint4*)(kp);
            kaB = *(const uint4*)(kp + 64 * 64);
            vaA = *(const uint4*)(vp);
            vaB = *(const uint4*)(vp + 64);
        }
        if (w & 1) {
            half_iter(Kc + 64 * 64, Vc, 8);
            half_iter(Kc, Vc, 0);
        } else {
            half_iter(Kc, Vc, 0);
            half_iter(Kc + 64 * 64, Vc, 8);
        }
        // stage next tile into the other buffer (latency hidden under compute)
        if (it < 31) {
            *(uint4*)&Kn[woffK]  = kaA;
            *(uint4*)&Kn[woffKB] = kaB;
            *(uint4*)&Vn[woffV]  = vaA;
            *(uint4*)&Vn[woffVB] = vaB;
        }
    };

    for (int it2 = 0; it2 < 32; it2 += 2) {
        tile_iter(it2,     &Ks[0],    &Vs[0],    &Ks[8192], &Vs[8192]);
        tile_iter(it2 + 1, &Ks[8192], &Vs[8192], &Ks[0],    &Vs[0]);
    }

    const int b = bh >> 3, h = bh & 7;
    #pragma unroll
    for (int r = 0; r < 4; ++r) {
        float inv = 1.f / lacc[r];
        int m = b * 4096 + q0 + w * 16 + 4 * g + r;
        #pragma unroll
        for (int nd = 0; nd < 4; ++nd) {
            int n = h * 64 + nd * 16 + c;
            Mo[(size_t)m * 512 + n] = f2bf(o[nd][r] * inv);
        }
    }
}

extern "C" void kernel_launch(void* const* d_in, const int* in_sizes, int n_in,
                              void* d_out, int out_size, void* d_ws, size_t ws_size,
                              hipStream_t stream) {
    const float* q  = (const float*)d_in[0];
    const float* Wq = (const float*)d_in[1];
    const float* bq = (const float*)d_in[2];
    const float* Wk = (const float*)d_in[3];
    const float* bk = (const float*)d_in[4];
    const float* Wv = (const float*)d_in[5];
    const float* bv = (const float*)d_in[6];
    const float* Wo = (const float*)d_in[7];
    const float* bo = (const float*)d_in[8];

    unsigned short* Qb = (unsigned short*)d_ws;            // 8 MB
    unsigned short* Kb = Qb + (size_t)16 * 4096 * 64;      // 8 MB
    unsigned short* Vt = Kb + (size_t)16 * 4096 * 64;      // 8 MB (V^T per head)
    unsigned short* Mg = Vt + (size_t)16 * 4096 * 64;      // merged bf16 [8192][512]

    dim3 gb(256);
    dim3 gqkv(64, 4, 3);
    gemm_qkv<<<gqkv, gb, 0, stream>>>(q, Wq, bq, Wk, bk, Wv, bv, Qb, Kb, Vt);

    dim3 ga(512), gba(512);
    attn128<<<ga, gba, 0, stream>>>(Qb, Kb, Vt, Mg);

    dim3 gg(64, 4);
    gemm_out<<<gg, gb, 0, stream>>>(Mg, Wo, bo, (float*)d_out);
}